// Round 6
// baseline (176.762 us; speedup 1.0000x reference)
//
#include <hip/hip_runtime.h>
#include <math.h>

#define NN 20000
#define EE 320000

using short8 = __attribute__((ext_vector_type(8))) short;
using f32x4  = __attribute__((ext_vector_type(4))) float;
using u16x4  = __attribute__((ext_vector_type(4))) unsigned short;

__device__ __forceinline__ unsigned short f2bf(float x) {
    union { float f; unsigned u; } v; v.f = x;
    unsigned r = (v.u + 0x7fffu + ((v.u >> 16) & 1u)) >> 16;
    return (unsigned short)r;
}
__device__ __forceinline__ float bf2f(unsigned short b) {
    union { unsigned u; float f; } v; v.u = ((unsigned)b) << 16;
    return v.f;
}
__device__ __forceinline__ float sigmoidf_(float x) { return 1.f / (1.f + __expf(-x)); }
__device__ __forceinline__ float tanhf_(float x) {
    float e = __expf(-2.f * x);
    return (1.f - e) / (1.f + e);
}
__device__ __forceinline__ float lrelu_(float x) { return x > 0.f ? x : 0.2f * x; }
__device__ __forceinline__ float elu_(float x) { return x > 0.f ? x : __expf(x) - 1.f; }

// ---------------- weight pack into MFMA B-fragment layout ----------------
struct PackDesc { const float* w; unsigned short* out; int O; int ldw; int mode; };
struct PackArgs { PackDesc d[10]; };

__global__ void k_pack(PackArgs args) {
    PackDesc d = args.d[blockIdx.y];
    int idx = blockIdx.x * 256 + threadIdx.x;
    if (d.mode == 1) {   // W2b: bond part of fc2_w, K=32 zero-padded
        if (idx >= 512) return;
        int t = idx >> 6, l = idx & 63;
        int lr = l & 15, lg = l >> 4;
        int ch = lr * 8 + t;
        short8 o;
        #pragma unroll
        for (int j = 0; j < 8; j++) {
            int k = lg * 8 + j;
            o[j] = (k < 16) ? (short)f2bf(d.w[(size_t)ch * 144 + 128 + k]) : (short)0;
        }
        *(short8*)(d.out + (size_t)idx * 8) = o;
        return;
    }
    int total = (d.O / 16) * 4 * 64;
    if (idx >= total) return;
    int l = idx & 63, rest = idx >> 6;
    int ko = rest & 3, no = rest >> 2;
    int row = no * 16 + (l & 15);
    int col0 = ko * 32 + ((l >> 4) * 8);
    const float* src = d.w + (size_t)row * d.ldw + col0;
    unsigned short o[8];
    #pragma unroll
    for (int j = 0; j < 8; j++) o[j] = f2bf(src[j]);
    #pragma unroll
    for (int j = 0; j < 8; j++) d.out[(size_t)idx * 8 + j] = o[j];
}

// ---------------- V1 front ----------------
__global__ __launch_bounds__(256) void k_v1_front(
    const float* __restrict__ atom,
    const unsigned short* __restrict__ Bfc1, const unsigned short* __restrict__ BW2a,
    const float* __restrict__ fc1_b, const float* __restrict__ fc2_b,
    const float* __restrict__ attw,
    float* __restrict__ g0, unsigned short* __restrict__ naBf,
    unsigned short* __restrict__ Ubf, float* __restrict__ adst)
{
    __shared__ float Xs[16][132];
    __shared__ unsigned short Ys2[16 * 128];
    const int tid = threadIdx.x, l = tid & 63, w = tid >> 6;
    const int lr = l & 15, lg = l >> 4;
    const int m0 = blockIdx.x * 16;

    f32x4 acc1[2] = {}, accU[2] = {};
    #pragma unroll
    for (int ko = 0; ko < 4; ko++) {
        const f32x4* ap = (const f32x4*)(atom + (size_t)(m0 + lr) * 128 + ko * 32 + lg * 8);
        f32x4 a0 = ap[0], a1 = ap[1];
        short8 af;
        #pragma unroll
        for (int j = 0; j < 4; j++) { af[j] = (short)f2bf(a0[j]); af[4 + j] = (short)f2bf(a1[j]); }
        #pragma unroll
        for (int i = 0; i < 2; i++) {
            int t = w * 2 + i;
            short8 b1 = *(const short8*)(Bfc1 + ((size_t)(t * 4 + ko) * 64 + l) * 8);
            acc1[i] = __builtin_amdgcn_mfma_f32_16x16x32_bf16(af, b1, acc1[i], 0, 0, 0);
            short8 bu = *(const short8*)(BW2a + ((size_t)(t * 4 + ko) * 64 + l) * 8);
            accU[i] = __builtin_amdgcn_mfma_f32_16x16x32_bf16(af, bu, accU[i], 0, 0, 0);
        }
    }
    #pragma unroll
    for (int i = 0; i < 2; i++) {
        int col = (w * 2 + i) * 16 + lr;
        float b1v = fc1_b[col], bUv = fc2_b[col];
        #pragma unroll
        for (int r = 0; r < 4; r++) {
            int row = lg * 4 + r;
            float v = lrelu_(acc1[i][r] + b1v);
            Xs[row][col] = v;
            Ys2[row * 128 + col] = f2bf(accU[i][r] + bUv);
        }
    }
    __syncthreads();
    *(short8*)(Ubf + (size_t)m0 * 128 + tid * 8) = *(const short8*)(Ys2 + tid * 8);
    {   // coalesced g0 write + bf16 copy + adst dot
        int row = tid >> 4, q = tid & 15;
        short8 tmp;
        float p = 0.f;
        float vv[8];
        #pragma unroll
        for (int j = 0; j < 8; j++) {
            float x = Xs[row][q * 8 + j];
            vv[j] = x;
            tmp[j] = (short)f2bf(x);
            p = fmaf(x, attw[q * 8 + j], p);
        }
        *(f32x4*)(g0 + (size_t)(m0 + row) * 128 + q * 8) = *(f32x4*)vv;
        *(f32x4*)(g0 + (size_t)(m0 + row) * 128 + q * 8 + 4) = *(f32x4*)(vv + 4);
        *(short8*)(naBf + (size_t)(m0 + row) * 128 + q * 8) = tmp;
        #pragma unroll
        for (int m = 1; m <= 8; m <<= 1) p += __shfl_xor(p, m, 16);
        if (q == 0) adst[m0 + row] = p;
    }
}

// ---------------- V1 edge logits ----------------
__global__ __launch_bounds__(256) void k_logits_v1(
    const unsigned short* __restrict__ U, const int* __restrict__ esrc,
    const float* __restrict__ bond, const unsigned short* __restrict__ BW2b,
    const float* __restrict__ attw, const float* __restrict__ attb1,
    const float* __restrict__ adst, float* __restrict__ logits)
{
    const int tid = threadIdx.x, l = tid & 63, w = tid >> 6;
    const int lr = l & 15, lg = l >> 4;
    const int n = blockIdx.x * 4 + w;
    const int e0 = n * 16;

    short8 af = {};
    if (lg < 2) {
        const f32x4* bp = (const f32x4*)(bond + (size_t)(e0 + lr) * 16 + lg * 8);
        f32x4 b0 = bp[0], b1 = bp[1];
        #pragma unroll
        for (int j = 0; j < 4; j++) { af[j] = (short)f2bf(b0[j]); af[4 + j] = (short)f2bf(b1[j]); }
    }
    f32x4 c[8];
    #pragma unroll
    for (int t = 0; t < 8; t++) {
        short8 bf = *(const short8*)(BW2b + (size_t)(t * 64 + l) * 8);
        f32x4 z = {};
        c[t] = __builtin_amdgcn_mfma_f32_16x16x32_bf16(af, bf, z, 0, 0, 0);
    }
    float aw[8];
    #pragma unroll
    for (int t = 0; t < 8; t++) aw[t] = attw[128 + lr * 8 + t];

    float s[4];
    #pragma unroll
    for (int r = 0; r < 4; r++) {
        int e = e0 + lg * 4 + r;
        int src = esrc[e];
        short8 u = *(const short8*)(U + (size_t)src * 128 + lr * 8);
        float a0 = 0.f;
        #pragma unroll
        for (int t = 0; t < 8; t++)
            a0 = fmaf(aw[t], lrelu_(c[t][r] + bf2f((unsigned short)u[t])), a0);
        s[r] = a0;
    }
    #pragma unroll
    for (int mk = 1; mk <= 8; mk <<= 1)
        #pragma unroll
        for (int r = 0; r < 4; r++) s[r] += __shfl_xor(s[r], mk, 16);
    if (lr == 0) {
        float anode = adst[n], ab = attb1[0];
        f32x4 o;
        #pragma unroll
        for (int r = 0; r < 4; r++) o[r] = lrelu_(anode + ab + s[r]);
        *(f32x4*)(logits + e0 + lg * 4) = o;
    }
}

// ---------------- aggregation pass: softmax + gather HALF of channels -------------
template<int MODE, int HALF>
__global__ __launch_bounds__(256) void k_agg(
    const float* __restrict__ logits, const float* __restrict__ aD,
    const float* __restrict__ bS, const float* __restrict__ b1,
    const int* __restrict__ esrc, const unsigned short* __restrict__ V,
    unsigned short* __restrict__ agg)
{
    const int tid = threadIdx.x;
    const int node = blockIdx.x * 16 + (tid >> 4);
    const int q = tid & 15;
    const int e = node * 16 + q;
    const int src = esrc[e];
    float lgt;
    if (MODE == 0) lgt = logits[e];
    else           lgt = lrelu_(aD[node] + bS[src] + b1[0]);
    float mx = lgt;
    #pragma unroll
    for (int mk = 1; mk <= 8; mk <<= 1) mx = fmaxf(mx, __shfl_xor(mx, mk, 16));
    float ex = __expf(lgt - mx);
    float den = ex;
    #pragma unroll
    for (int mk = 1; mk <= 8; mk <<= 1) den += __shfl_xor(den, mk, 16);
    float wq = ex / den;
    float s0 = 0.f, s1 = 0.f, s2 = 0.f, s3 = 0.f;
    #pragma unroll
    for (int i = 0; i < 16; i++) {
        float wi = __shfl(wq, i, 16);
        int si = __shfl(src, i, 16);
        u16x4 v = *(const u16x4*)(V + (size_t)si * 128 + HALF * 64 + q * 4);
        s0 = fmaf(wi, bf2f(v[0]), s0);
        s1 = fmaf(wi, bf2f(v[1]), s1);
        s2 = fmaf(wi, bf2f(v[2]), s2);
        s3 = fmaf(wi, bf2f(v[3]), s3);
    }
    u16x4 o;
    o[0] = f2bf(s0); o[1] = f2bf(s1); o[2] = f2bf(s2); o[3] = f2bf(s3);
    *(u16x4*)(agg + (size_t)node * 128 + HALF * 64 + q * 4) = o;
}

// ---------------- GRU: 32-row blocks ----------------
// pre-GEMM ctx = elu(agg@Wpre+b); GRU GEMMs (B-frag reuse over 2 row-tiles);
// gates in frag domain -> LDS; coalesced writes. FRONT: aD/bS dots (f32 h).
// FINAL: avg + lin + gelu with coalesced writes.
template<int FRONT, int FINAL>
__global__ __launch_bounds__(256) void k_gru(
    const unsigned short* __restrict__ agg,
    const unsigned short* __restrict__ Bpre, const float* __restrict__ bpre,
    const unsigned short* __restrict__ hBf,
    const unsigned short* __restrict__ Bih, const unsigned short* __restrict__ Bhh,
    const float* __restrict__ bih, const float* __restrict__ bhh,
    const float* __restrict__ hprevF, float* __restrict__ houtF,
    unsigned short* __restrict__ houtBf,
    const float* __restrict__ w2att, float* __restrict__ aDOut, float* __restrict__ bSOut,
    const float* __restrict__ as0, const float* __restrict__ as1,
    const unsigned short* __restrict__ Blin, const float* __restrict__ linb,
    float* __restrict__ avgOut, float* __restrict__ outF)
{
    __shared__ unsigned short ctxS[32][136];
    __shared__ float hoS[32][132];
    const int tid = threadIdx.x, l = tid & 63, w = tid >> 6;
    const int lr = l & 15, lg = l >> 4;
    const int m0 = blockIdx.x * 32;

    // ---- pre-GEMM ----
    f32x4 accp[2][2] = {};
    #pragma unroll
    for (int ko = 0; ko < 4; ko++) {
        short8 a0 = *(const short8*)(agg + (size_t)(m0 + lr) * 128 + ko * 32 + lg * 8);
        short8 a1 = *(const short8*)(agg + (size_t)(m0 + 16 + lr) * 128 + ko * 32 + lg * 8);
        #pragma unroll
        for (int i = 0; i < 2; i++) {
            int t = w * 2 + i;
            short8 bf = *(const short8*)(Bpre + ((size_t)(t * 4 + ko) * 64 + l) * 8);
            accp[0][i] = __builtin_amdgcn_mfma_f32_16x16x32_bf16(a0, bf, accp[0][i], 0, 0, 0);
            accp[1][i] = __builtin_amdgcn_mfma_f32_16x16x32_bf16(a1, bf, accp[1][i], 0, 0, 0);
        }
    }
    #pragma unroll
    for (int rt = 0; rt < 2; rt++)
        #pragma unroll
        for (int i = 0; i < 2; i++) {
            int col = (w * 2 + i) * 16 + lr;
            float bb = bpre[col];
            #pragma unroll
            for (int r = 0; r < 4; r++)
                ctxS[rt * 16 + lg * 4 + r][col] = f2bf(elu_(accp[rt][i][r] + bb));
        }
    // prefetch hprev (coalesced) into hoS
    {
        int row = tid >> 3, c0 = (tid & 7) * 16;
        const f32x4* hp = (const f32x4*)(hprevF + (size_t)(m0 + row) * 128 + c0);
        #pragma unroll
        for (int k = 0; k < 4; k++) *(f32x4*)&hoS[row][c0 + k * 4] = hp[k];
    }
    __syncthreads();

    // ---- GRU GEMMs ----
    f32x4 acc[2][12] = {};
    #pragma unroll
    for (int ko = 0; ko < 4; ko++) {
        short8 afc0 = *(const short8*)&ctxS[lr][ko * 32 + lg * 8];
        short8 afc1 = *(const short8*)&ctxS[16 + lr][ko * 32 + lg * 8];
        short8 afh0 = *(const short8*)(hBf + (size_t)(m0 + lr) * 128 + ko * 32 + lg * 8);
        short8 afh1 = *(const short8*)(hBf + (size_t)(m0 + 16 + lr) * 128 + ko * 32 + lg * 8);
        #pragma unroll
        for (int i2 = 0; i2 < 6; i2++) {
            short8 bi = *(const short8*)(Bih + ((size_t)((w + 4 * i2) * 4 + ko) * 64 + l) * 8);
            acc[0][i2] = __builtin_amdgcn_mfma_f32_16x16x32_bf16(afc0, bi, acc[0][i2], 0, 0, 0);
            acc[1][i2] = __builtin_amdgcn_mfma_f32_16x16x32_bf16(afc1, bi, acc[1][i2], 0, 0, 0);
            short8 bh = *(const short8*)(Bhh + ((size_t)((w + 4 * i2) * 4 + ko) * 64 + l) * 8);
            acc[0][6 + i2] = __builtin_amdgcn_mfma_f32_16x16x32_bf16(afh0, bh, acc[0][6 + i2], 0, 0, 0);
            acc[1][6 + i2] = __builtin_amdgcn_mfma_f32_16x16x32_bf16(afh1, bh, acc[1][6 + i2], 0, 0, 0);
        }
    }
    // ---- gates (fragment domain, hp from LDS, ho back to LDS) ----
    #pragma unroll
    for (int rt = 0; rt < 2; rt++)
        #pragma unroll
        for (int i = 0; i < 2; i++) {
            const int c = (w + 4 * i) * 16 + lr;
            const float br = bih[c] + bhh[c];
            const float bz = bih[c + 128] + bhh[c + 128];
            const float bin_ = bih[c + 256];
            const float bhn = bhh[c + 256];
            #pragma unroll
            for (int r = 0; r < 4; r++) {
                const int lrow = rt * 16 + lg * 4 + r;
                float rg = sigmoidf_(acc[rt][i][r] + acc[rt][6 + i][r] + br);
                float zg = sigmoidf_(acc[rt][i + 2][r] + acc[rt][8 + i][r] + bz);
                float ng = tanhf_(acc[rt][i + 4][r] + bin_ + rg * (acc[rt][10 + i][r] + bhn));
                float hp = hoS[lrow][c];
                hoS[lrow][c] = fmaf(zg, hp - ng, ng);
            }
        }
    __syncthreads();

    // ---- coalesced h writes ----
    {
        int row = tid >> 3, c0 = (tid & 7) * 16;
        float v[16];
        #pragma unroll
        for (int k = 0; k < 16; k++) v[k] = hoS[row][c0 + k];
        f32x4* dst = (f32x4*)(houtF + (size_t)(m0 + row) * 128 + c0);
        #pragma unroll
        for (int k = 0; k < 4; k++) dst[k] = *(f32x4*)&v[k * 4];
        if (FINAL == 0) {
            short8 p0, p1;
            #pragma unroll
            for (int k = 0; k < 8; k++) { p0[k] = (short)f2bf(v[k]); p1[k] = (short)f2bf(v[8 + k]); }
            *(short8*)(houtBf + (size_t)(m0 + row) * 128 + c0) = p0;
            *(short8*)(houtBf + (size_t)(m0 + row) * 128 + c0 + 8) = p1;
        }
    }

    if (FRONT) {
        #pragma unroll
        for (int rh = 0; rh < 2; rh++) {
            int row = rh * 16 + (tid >> 4), q = tid & 15;
            float pa = 0.f, pb = 0.f;
            #pragma unroll
            for (int j = 0; j < 8; j++) {
                float x = hoS[row][q * 8 + j];
                pa = fmaf(x, w2att[q * 8 + j], pa);
                pb = fmaf(x, w2att[128 + q * 8 + j], pb);
            }
            #pragma unroll
            for (int m = 1; m <= 8; m <<= 1) {
                pa += __shfl_xor(pa, m, 16);
                pb += __shfl_xor(pb, m, 16);
            }
            if (q == 0) { aDOut[m0 + row] = pa; bSOut[m0 + row] = pb; }
        }
    }

    if (FINAL) {
        // avg pass (coalesced): read as0/as1, h from hoS; write avgOut; stage bf16 av
        {
            int row = tid >> 3, c0 = (tid & 7) * 16;
            const f32x4* p0 = (const f32x4*)(as0 + (size_t)(m0 + row) * 128 + c0);
            const f32x4* p1 = (const f32x4*)(as1 + (size_t)(m0 + row) * 128 + c0);
            f32x4* pav = (f32x4*)(avgOut + (size_t)(m0 + row) * 128 + c0);
            #pragma unroll
            for (int k = 0; k < 4; k++) {
                f32x4 x0 = p0[k], x1 = p1[k];
                f32x4 av;
                #pragma unroll
                for (int j = 0; j < 4; j++) {
                    av[j] = (x0[j] + x1[j] + hoS[row][c0 + k * 4 + j]) * (1.f / 3.f);
                }
                pav[k] = av;
                #pragma unroll
                for (int j = 0; j < 4; j++) ctxS[row][c0 + k * 4 + j] = f2bf(av[j]);
            }
        }
        __syncthreads();
        // lin GEMM + gelu
        f32x4 acc2[2][2] = {};
        #pragma unroll
        for (int ko = 0; ko < 4; ko++) {
            short8 a0 = *(const short8*)&ctxS[lr][ko * 32 + lg * 8];
            short8 a1 = *(const short8*)&ctxS[16 + lr][ko * 32 + lg * 8];
            #pragma unroll
            for (int i = 0; i < 2; i++) {
                int t = w * 2 + i;
                short8 bf = *(const short8*)(Blin + ((size_t)(t * 4 + ko) * 64 + l) * 8);
                acc2[0][i] = __builtin_amdgcn_mfma_f32_16x16x32_bf16(a0, bf, acc2[0][i], 0, 0, 0);
                acc2[1][i] = __builtin_amdgcn_mfma_f32_16x16x32_bf16(a1, bf, acc2[1][i], 0, 0, 0);
            }
        }
        __syncthreads();
        #pragma unroll
        for (int rt = 0; rt < 2; rt++)
            #pragma unroll
            for (int i = 0; i < 2; i++) {
                int col = (w * 2 + i) * 16 + lr;
                float bb = linb[col];
                #pragma unroll
                for (int r = 0; r < 4; r++) {
                    float vv = acc2[rt][i][r] + bb;
                    hoS[rt * 16 + lg * 4 + r][col] =
                        0.5f * vv * (1.f + erff(vv * 0.70710678118654752f));
                }
            }
        __syncthreads();
        {
            int row = tid >> 3, c0 = (tid & 7) * 16;
            f32x4* dst = (f32x4*)(outF + (size_t)(m0 + row) * 128 + c0);
            #pragma unroll
            for (int k = 0; k < 4; k++) {
                f32x4 v;
                #pragma unroll
                for (int j = 0; j < 4; j++) v[j] = hoS[row][c0 + k * 4 + j];
                dst[k] = v;
            }
        }
    }
}

extern "C" void kernel_launch(void* const* d_in, const int* in_sizes, int n_in,
                              void* d_out, int out_size, void* d_ws, size_t ws_size,
                              hipStream_t stream) {
    const float* atom     = (const float*)d_in[0];
    const int*   esrc     = (const int*)d_in[1];
    const float* bond     = (const float*)d_in[3];
    const float* fc1_w    = (const float*)d_in[4];
    const float* fc1_b    = (const float*)d_in[5];
    const float* fc2_w    = (const float*)d_in[6];
    const float* fc2_b    = (const float*)d_in[7];
    const float* att_w    = (const float*)d_in[8];
    const float* att_b    = (const float*)d_in[9];
    const float* attend_w = (const float*)d_in[10];
    const float* attend_b = (const float*)d_in[11];
    const float* gih1     = (const float*)d_in[12];
    const float* ghh1     = (const float*)d_in[13];
    const float* bih1     = (const float*)d_in[14];
    const float* bhh1     = (const float*)d_in[15];
    const float* fc1v2_w  = (const float*)d_in[16];
    const float* fc1v2_b  = (const float*)d_in[17];
    const float* fc2v2_w  = (const float*)d_in[18];
    const float* fc2v2_b  = (const float*)d_in[19];
    const float* gih2     = (const float*)d_in[20];
    const float* ghh2     = (const float*)d_in[21];
    const float* bih2     = (const float*)d_in[22];
    const float* bhh2     = (const float*)d_in[23];
    const float* lin_w    = (const float*)d_in[24];
    const float* lin_b    = (const float*)d_in[25];

    char* wsb = (char*)d_ws;
    size_t off = 0;
    auto allocB = [&](size_t bytes) {
        size_t o = off; off = (off + bytes + 255) & ~(size_t)255; return o;
    };
    unsigned short* Bfc1   = (unsigned short*)(wsb + allocB(128 * 128 * 2));
    unsigned short* Batt   = (unsigned short*)(wsb + allocB(128 * 128 * 2));
    unsigned short* BW2a   = (unsigned short*)(wsb + allocB(128 * 128 * 2));
    unsigned short* BW2b   = (unsigned short*)(wsb + allocB(512 * 8 * 2));
    unsigned short* Bgih1  = (unsigned short*)(wsb + allocB(384 * 128 * 2));
    unsigned short* Bghh1  = (unsigned short*)(wsb + allocB(384 * 128 * 2));
    unsigned short* Bfc2v2 = (unsigned short*)(wsb + allocB(128 * 128 * 2));
    unsigned short* Bgih2  = (unsigned short*)(wsb + allocB(384 * 128 * 2));
    unsigned short* Bghh2  = (unsigned short*)(wsb + allocB(384 * 128 * 2));
    unsigned short* Blin   = (unsigned short*)(wsb + allocB(128 * 128 * 2));
    unsigned short* naBf   = (unsigned short*)(wsb + allocB((size_t)NN * 128 * 2));
    unsigned short* Ubf    = (unsigned short*)(wsb + allocB((size_t)NN * 128 * 2));
    unsigned short* aggBf  = (unsigned short*)(wsb + allocB((size_t)NN * 128 * 2));
    unsigned short* h1Bf   = (unsigned short*)(wsb + allocB((size_t)NN * 128 * 2));
    unsigned short* h2Bf   = (unsigned short*)(wsb + allocB((size_t)NN * 128 * 2));
    float* logits = (float*)(wsb + allocB((size_t)EE * 4));
    float* adst   = (float*)(wsb + allocB((size_t)NN * 4));
    float* aD     = (float*)(wsb + allocB((size_t)NN * 4));
    float* bS     = (float*)(wsb + allocB((size_t)NN * 4));
    (void)ws_size;

    float* out0 = (float*)d_out;
    float* as0  = out0 + (size_t)NN * 128;
    float* as1  = as0 + (size_t)NN * 128;
    float* as2  = as1 + (size_t)NN * 128;
    float* g0   = out0 + (size_t)4 * NN * 128;
    float* avg  = out0 + (size_t)5 * NN * 128;

    PackArgs pa;
    pa.d[0] = { fc1_w,    Bfc1,   128, 128, 0 };
    pa.d[1] = { attend_w, Batt,   128, 128, 0 };
    pa.d[2] = { fc2_w,    BW2a,   128, 144, 0 };
    pa.d[3] = { gih1,     Bgih1,  384, 128, 0 };
    pa.d[4] = { ghh1,     Bghh1,  384, 128, 0 };
    pa.d[5] = { fc2v2_w,  Bfc2v2, 128, 128, 0 };
    pa.d[6] = { gih2,     Bgih2,  384, 128, 0 };
    pa.d[7] = { ghh2,     Bghh2,  384, 128, 0 };
    pa.d[8] = { lin_w,    Blin,   128, 128, 0 };
    pa.d[9] = { fc2_w,    BW2b,   0,   0,   1 };
    k_pack<<<dim3(24, 10), 256, 0, stream>>>(pa);

    const int GB = NN / 16;   // 1250
    const int GB32 = NN / 32; // 625

    // ---- V1 ----
    k_v1_front<<<GB, 256, 0, stream>>>(atom, Bfc1, BW2a, fc1_b, fc2_b, att_w,
                                       g0, naBf, Ubf, adst);
    k_logits_v1<<<NN / 4, 256, 0, stream>>>(Ubf, esrc, bond, BW2b, att_w, att_b,
                                            adst, logits);
    k_agg<0, 0><<<GB, 256, 0, stream>>>(logits, nullptr, nullptr, nullptr, esrc, naBf, aggBf);
    k_agg<0, 1><<<GB, 256, 0, stream>>>(logits, nullptr, nullptr, nullptr, esrc, naBf, aggBf);
    k_gru<1, 0><<<GB32, 256, 0, stream>>>(
        aggBf, Batt, attend_b,
        naBf, Bgih1, Bghh1, bih1, bhh1, g0, as0, h1Bf,
        fc1v2_w, aD, bS,
        nullptr, nullptr, nullptr, nullptr, nullptr, nullptr);

    // ---- V2 layer 2 ----
    k_agg<1, 0><<<GB, 256, 0, stream>>>(nullptr, aD, bS, fc1v2_b, esrc, h1Bf, aggBf);
    k_agg<1, 1><<<GB, 256, 0, stream>>>(nullptr, aD, bS, fc1v2_b, esrc, h1Bf, aggBf);
    k_gru<1, 0><<<GB32, 256, 0, stream>>>(
        aggBf, Bfc2v2, fc2v2_b,
        h1Bf, Bgih2, Bghh2, bih2, bhh2, as0, as1, h2Bf,
        fc1v2_w, aD, bS,
        nullptr, nullptr, nullptr, nullptr, nullptr, nullptr);

    // ---- V2 layer 3 + final ----
    k_agg<1, 0><<<GB, 256, 0, stream>>>(nullptr, aD, bS, fc1v2_b, esrc, h2Bf, aggBf);
    k_agg<1, 1><<<GB, 256, 0, stream>>>(nullptr, aD, bS, fc1v2_b, esrc, h2Bf, aggBf);
    k_gru<0, 1><<<GB32, 256, 0, stream>>>(
        aggBf, Bfc2v2, fc2v2_b,
        h2Bf, Bgih2, Bghh2, bih2, bhh2, as1, as2, nullptr,
        nullptr, nullptr, nullptr,
        as0, as1, Blin, lin_b, avg, out0);
}

// Round 7
// 151.026 us; speedup vs baseline: 1.1704x; 1.1704x over previous
//
#include <hip/hip_runtime.h>
#include <math.h>

#define NN 20000
#define EE 320000

using short8 = __attribute__((ext_vector_type(8))) short;
using f32x4  = __attribute__((ext_vector_type(4))) float;
using u16x4  = __attribute__((ext_vector_type(4))) unsigned short;

__device__ __forceinline__ unsigned short f2bf(float x) {
    union { float f; unsigned u; } v; v.f = x;
    unsigned r = (v.u + 0x7fffu + ((v.u >> 16) & 1u)) >> 16;
    return (unsigned short)r;
}
__device__ __forceinline__ float bf2f(unsigned short b) {
    union { unsigned u; float f; } v; v.u = ((unsigned)b) << 16;
    return v.f;
}
__device__ __forceinline__ float sigmoidf_(float x) { return 1.f / (1.f + __expf(-x)); }
__device__ __forceinline__ float tanhf_(float x) {
    float e = __expf(-2.f * x);
    return (1.f - e) / (1.f + e);
}
__device__ __forceinline__ float lrelu_(float x) { return x > 0.f ? x : 0.2f * x; }
__device__ __forceinline__ float elu_(float x) { return x > 0.f ? x : __expf(x) - 1.f; }

// ---------------- weight pack into MFMA B-fragment layout ----------------
struct PackDesc { const float* w; unsigned short* out; int O; int ldw; int mode; };
struct PackArgs { PackDesc d[10]; };

__global__ void k_pack(PackArgs args) {
    PackDesc d = args.d[blockIdx.y];
    int idx = blockIdx.x * 256 + threadIdx.x;
    if (d.mode == 1) {   // W2b: bond part of fc2_w, K=32 zero-padded
        if (idx >= 512) return;
        int t = idx >> 6, l = idx & 63;
        int lr = l & 15, lg = l >> 4;
        int ch = lr * 8 + t;
        short8 o;
        #pragma unroll
        for (int j = 0; j < 8; j++) {
            int k = lg * 8 + j;
            o[j] = (k < 16) ? (short)f2bf(d.w[(size_t)ch * 144 + 128 + k]) : (short)0;
        }
        *(short8*)(d.out + (size_t)idx * 8) = o;
        return;
    }
    int total = (d.O / 16) * 4 * 64;
    if (idx >= total) return;
    int l = idx & 63, rest = idx >> 6;
    int ko = rest & 3, no = rest >> 2;
    int row = no * 16 + (l & 15);
    int col0 = ko * 32 + ((l >> 4) * 8);
    const float* src = d.w + (size_t)row * d.ldw + col0;
    unsigned short o[8];
    #pragma unroll
    for (int j = 0; j < 8; j++) o[j] = f2bf(src[j]);
    #pragma unroll
    for (int j = 0; j < 8; j++) d.out[(size_t)idx * 8 + j] = o[j];
}

// ---------------- V1 front ----------------
__global__ __launch_bounds__(256) void k_v1_front(
    const float* __restrict__ atom,
    const unsigned short* __restrict__ Bfc1, const unsigned short* __restrict__ BW2a,
    const float* __restrict__ fc1_b, const float* __restrict__ fc2_b,
    const float* __restrict__ attw,
    float* __restrict__ g0, unsigned short* __restrict__ naBf,
    unsigned short* __restrict__ Ubf, float* __restrict__ adst)
{
    __shared__ float Xs[16][132];
    __shared__ unsigned short Ys2[16 * 128];
    const int tid = threadIdx.x, l = tid & 63, w = tid >> 6;
    const int lr = l & 15, lg = l >> 4;
    const int m0 = blockIdx.x * 16;

    f32x4 acc1[2] = {}, accU[2] = {};
    #pragma unroll
    for (int ko = 0; ko < 4; ko++) {
        const f32x4* ap = (const f32x4*)(atom + (size_t)(m0 + lr) * 128 + ko * 32 + lg * 8);
        f32x4 a0 = ap[0], a1 = ap[1];
        short8 af;
        #pragma unroll
        for (int j = 0; j < 4; j++) { af[j] = (short)f2bf(a0[j]); af[4 + j] = (short)f2bf(a1[j]); }
        #pragma unroll
        for (int i = 0; i < 2; i++) {
            int t = w * 2 + i;
            short8 b1 = *(const short8*)(Bfc1 + ((size_t)(t * 4 + ko) * 64 + l) * 8);
            acc1[i] = __builtin_amdgcn_mfma_f32_16x16x32_bf16(af, b1, acc1[i], 0, 0, 0);
            short8 bu = *(const short8*)(BW2a + ((size_t)(t * 4 + ko) * 64 + l) * 8);
            accU[i] = __builtin_amdgcn_mfma_f32_16x16x32_bf16(af, bu, accU[i], 0, 0, 0);
        }
    }
    #pragma unroll
    for (int i = 0; i < 2; i++) {
        int col = (w * 2 + i) * 16 + lr;
        float b1v = fc1_b[col], bUv = fc2_b[col];
        #pragma unroll
        for (int r = 0; r < 4; r++) {
            int row = lg * 4 + r;
            float v = lrelu_(acc1[i][r] + b1v);
            Xs[row][col] = v;
            Ys2[row * 128 + col] = f2bf(accU[i][r] + bUv);
        }
    }
    __syncthreads();
    *(short8*)(Ubf + (size_t)m0 * 128 + tid * 8) = *(const short8*)(Ys2 + tid * 8);
    {
        int row = tid >> 4, q = tid & 15;
        short8 tmp;
        float p = 0.f;
        float vv[8];
        #pragma unroll
        for (int j = 0; j < 8; j++) {
            float x = Xs[row][q * 8 + j];
            vv[j] = x;
            tmp[j] = (short)f2bf(x);
            p = fmaf(x, attw[q * 8 + j], p);
        }
        *(f32x4*)(g0 + (size_t)(m0 + row) * 128 + q * 8) = *(f32x4*)vv;
        *(f32x4*)(g0 + (size_t)(m0 + row) * 128 + q * 8 + 4) = *(f32x4*)(vv + 4);
        *(short8*)(naBf + (size_t)(m0 + row) * 128 + q * 8) = tmp;
        #pragma unroll
        for (int m = 1; m <= 8; m <<= 1) p += __shfl_xor(p, m, 16);
        if (q == 0) adst[m0 + row] = p;
    }
}

// ---------------- V1 edge logits ----------------
__global__ __launch_bounds__(256) void k_logits_v1(
    const unsigned short* __restrict__ U, const int* __restrict__ esrc,
    const float* __restrict__ bond, const unsigned short* __restrict__ BW2b,
    const float* __restrict__ attw, const float* __restrict__ attb1,
    const float* __restrict__ adst, float* __restrict__ logits)
{
    const int tid = threadIdx.x, l = tid & 63, w = tid >> 6;
    const int lr = l & 15, lg = l >> 4;
    const int n = blockIdx.x * 4 + w;
    const int e0 = n * 16;

    short8 af = {};
    if (lg < 2) {
        const f32x4* bp = (const f32x4*)(bond + (size_t)(e0 + lr) * 16 + lg * 8);
        f32x4 b0 = bp[0], b1 = bp[1];
        #pragma unroll
        for (int j = 0; j < 4; j++) { af[j] = (short)f2bf(b0[j]); af[4 + j] = (short)f2bf(b1[j]); }
    }
    f32x4 c[8];
    #pragma unroll
    for (int t = 0; t < 8; t++) {
        short8 bf = *(const short8*)(BW2b + (size_t)(t * 64 + l) * 8);
        f32x4 z = {};
        c[t] = __builtin_amdgcn_mfma_f32_16x16x32_bf16(af, bf, z, 0, 0, 0);
    }
    float aw[8];
    #pragma unroll
    for (int t = 0; t < 8; t++) aw[t] = attw[128 + lr * 8 + t];

    float s[4];
    #pragma unroll
    for (int r = 0; r < 4; r++) {
        int e = e0 + lg * 4 + r;
        int src = esrc[e];
        short8 u = *(const short8*)(U + (size_t)src * 128 + lr * 8);
        float a0 = 0.f;
        #pragma unroll
        for (int t = 0; t < 8; t++)
            a0 = fmaf(aw[t], lrelu_(c[t][r] + bf2f((unsigned short)u[t])), a0);
        s[r] = a0;
    }
    #pragma unroll
    for (int mk = 1; mk <= 8; mk <<= 1)
        #pragma unroll
        for (int r = 0; r < 4; r++) s[r] += __shfl_xor(s[r], mk, 16);
    if (lr == 0) {
        float anode = adst[n], ab = attb1[0];
        f32x4 o;
        #pragma unroll
        for (int r = 0; r < 4; r++) o[r] = lrelu_(anode + ab + s[r]);
        *(f32x4*)(logits + e0 + lg * 4) = o;
    }
}

// ---------------- aggregation pass: softmax + gather HALF of channels -------------
template<int MODE, int HALF>
__global__ __launch_bounds__(256) void k_agg(
    const float* __restrict__ logits, const float* __restrict__ aD,
    const float* __restrict__ bS, const float* __restrict__ b1,
    const int* __restrict__ esrc, const unsigned short* __restrict__ V,
    unsigned short* __restrict__ agg)
{
    const int tid = threadIdx.x;
    const int node = blockIdx.x * 16 + (tid >> 4);
    const int q = tid & 15;
    const int e = node * 16 + q;
    const int src = esrc[e];
    float lgt;
    if (MODE == 0) lgt = logits[e];
    else           lgt = lrelu_(aD[node] + bS[src] + b1[0]);
    float mx = lgt;
    #pragma unroll
    for (int mk = 1; mk <= 8; mk <<= 1) mx = fmaxf(mx, __shfl_xor(mx, mk, 16));
    float ex = __expf(lgt - mx);
    float den = ex;
    #pragma unroll
    for (int mk = 1; mk <= 8; mk <<= 1) den += __shfl_xor(den, mk, 16);
    float wq = ex / den;
    float s0 = 0.f, s1 = 0.f, s2 = 0.f, s3 = 0.f;
    #pragma unroll
    for (int i = 0; i < 16; i++) {
        float wi = __shfl(wq, i, 16);
        int si = __shfl(src, i, 16);
        u16x4 v = *(const u16x4*)(V + (size_t)si * 128 + HALF * 64 + q * 4);
        s0 = fmaf(wi, bf2f(v[0]), s0);
        s1 = fmaf(wi, bf2f(v[1]), s1);
        s2 = fmaf(wi, bf2f(v[2]), s2);
        s3 = fmaf(wi, bf2f(v[3]), s3);
    }
    u16x4 o;
    o[0] = f2bf(s0); o[1] = f2bf(s1); o[2] = f2bf(s2); o[3] = f2bf(s3);
    *(u16x4*)(agg + (size_t)node * 128 + HALF * 64 + q * 4) = o;
}

// ---------------- GRU: 512 threads (8 waves), 16-row blocks ----------------
// Wave w owns channel-tile w: output tiles w (r), w+8 (z), w+16 (n) for ih & hh.
// pre-GEMM: wave w computes ctx tile w. FINAL: lin tile w.
template<int FRONT, int FINAL>
__global__ __launch_bounds__(512) void k_gru(
    const unsigned short* __restrict__ agg,
    const unsigned short* __restrict__ Bpre, const float* __restrict__ bpre,
    const unsigned short* __restrict__ hBf,
    const unsigned short* __restrict__ Bih, const unsigned short* __restrict__ Bhh,
    const float* __restrict__ bih, const float* __restrict__ bhh,
    const float* __restrict__ hprevF, float* __restrict__ houtF,
    unsigned short* __restrict__ houtBf,
    const float* __restrict__ w2att, float* __restrict__ aDOut, float* __restrict__ bSOut,
    const float* __restrict__ as0, const float* __restrict__ as1,
    const unsigned short* __restrict__ Blin, const float* __restrict__ linb,
    float* __restrict__ avgOut, float* __restrict__ outF)
{
    __shared__ unsigned short ctxS[16][136];
    __shared__ float hoS[16][132];
    const int tid = threadIdx.x, l = tid & 63, w = tid >> 6;   // w in 0..7
    const int lr = l & 15, lg = l >> 4;
    const int m0 = blockIdx.x * 16;
    const int crow = tid >> 5, ccol = (tid & 31) * 4;          // coalesced r/w mapping

    // prefetch hprev (coalesced) into hoS
    *(f32x4*)&hoS[crow][ccol] = *(const f32x4*)(hprevF + (size_t)(m0 + crow) * 128 + ccol);

    // ---- pre-GEMM: ctx = elu(agg @ Wpre^T + b), wave w -> tile w ----
    f32x4 accp = {};
    #pragma unroll
    for (int ko = 0; ko < 4; ko++) {
        short8 af = *(const short8*)(agg + (size_t)(m0 + lr) * 128 + ko * 32 + lg * 8);
        short8 bf = *(const short8*)(Bpre + ((size_t)(w * 4 + ko) * 64 + l) * 8);
        accp = __builtin_amdgcn_mfma_f32_16x16x32_bf16(af, bf, accp, 0, 0, 0);
    }
    {
        const int col = w * 16 + lr;
        const float bb = bpre[col];
        #pragma unroll
        for (int r = 0; r < 4; r++)
            ctxS[lg * 4 + r][col] = f2bf(elu_(accp[r] + bb));
    }
    __syncthreads();

    // ---- GRU GEMMs: 6 accumulators per wave ----
    f32x4 ai[3] = {}, ah[3] = {};
    #pragma unroll
    for (int ko = 0; ko < 4; ko++) {
        short8 afc = *(const short8*)&ctxS[lr][ko * 32 + lg * 8];
        short8 afh = *(const short8*)(hBf + (size_t)(m0 + lr) * 128 + ko * 32 + lg * 8);
        #pragma unroll
        for (int g = 0; g < 3; g++) {
            int t = w + 8 * g;
            short8 bi = *(const short8*)(Bih + ((size_t)(t * 4 + ko) * 64 + l) * 8);
            ai[g] = __builtin_amdgcn_mfma_f32_16x16x32_bf16(afc, bi, ai[g], 0, 0, 0);
            short8 bh = *(const short8*)(Bhh + ((size_t)(t * 4 + ko) * 64 + l) * 8);
            ah[g] = __builtin_amdgcn_mfma_f32_16x16x32_bf16(afh, bh, ah[g], 0, 0, 0);
        }
    }
    // ---- gates: channel c = w*16+lr, rows lg*4+r (unique per thread) ----
    {
        const int c = w * 16 + lr;
        const float br = bih[c] + bhh[c];
        const float bz = bih[c + 128] + bhh[c + 128];
        const float bin_ = bih[c + 256];
        const float bhn = bhh[c + 256];
        #pragma unroll
        for (int r = 0; r < 4; r++) {
            const int lrow = lg * 4 + r;
            float rg = sigmoidf_(ai[0][r] + ah[0][r] + br);
            float zg = sigmoidf_(ai[1][r] + ah[1][r] + bz);
            float ng = tanhf_(ai[2][r] + bin_ + rg * (ah[2][r] + bhn));
            float hp = hoS[lrow][c];
            hoS[lrow][c] = fmaf(zg, hp - ng, ng);
        }
    }
    __syncthreads();

    // ---- coalesced h writes ----
    {
        float v[4];
        #pragma unroll
        for (int k = 0; k < 4; k++) v[k] = hoS[crow][ccol + k];
        *(f32x4*)(houtF + (size_t)(m0 + crow) * 128 + ccol) = *(f32x4*)v;
        if (FINAL == 0) {
            u16x4 p;
            #pragma unroll
            for (int k = 0; k < 4; k++) p[k] = f2bf(v[k]);
            *(u16x4*)(houtBf + (size_t)(m0 + crow) * 128 + ccol) = p;
        }
    }

    if (FRONT) {
        if (tid < 256) {
            int row = tid >> 4, q = tid & 15;
            float pa = 0.f, pb = 0.f;
            #pragma unroll
            for (int j = 0; j < 8; j++) {
                float x = hoS[row][q * 8 + j];
                pa = fmaf(x, w2att[q * 8 + j], pa);
                pb = fmaf(x, w2att[128 + q * 8 + j], pb);
            }
            #pragma unroll
            for (int m = 1; m <= 8; m <<= 1) {
                pa += __shfl_xor(pa, m, 16);
                pb += __shfl_xor(pb, m, 16);
            }
            if (q == 0) { aDOut[m0 + row] = pa; bSOut[m0 + row] = pb; }
        }
    }

    if (FINAL) {
        // avg (coalesced) -> avgOut + ctxS(bf16)
        {
            f32x4 x0 = *(const f32x4*)(as0 + (size_t)(m0 + crow) * 128 + ccol);
            f32x4 x1 = *(const f32x4*)(as1 + (size_t)(m0 + crow) * 128 + ccol);
            f32x4 av;
            #pragma unroll
            for (int j = 0; j < 4; j++)
                av[j] = (x0[j] + x1[j] + hoS[crow][ccol + j]) * (1.f / 3.f);
            *(f32x4*)(avgOut + (size_t)(m0 + crow) * 128 + ccol) = av;
            #pragma unroll
            for (int j = 0; j < 4; j++) ctxS[crow][ccol + j] = f2bf(av[j]);
        }
        __syncthreads();
        // lin GEMM: wave w -> tile w
        f32x4 acc2 = {};
        #pragma unroll
        for (int ko = 0; ko < 4; ko++) {
            short8 af = *(const short8*)&ctxS[lr][ko * 32 + lg * 8];
            short8 bf = *(const short8*)(Blin + ((size_t)(w * 4 + ko) * 64 + l) * 8);
            acc2 = __builtin_amdgcn_mfma_f32_16x16x32_bf16(af, bf, acc2, 0, 0, 0);
        }
        {
            const int col = w * 16 + lr;
            const float bb = linb[col];
            #pragma unroll
            for (int r = 0; r < 4; r++) {
                float vv = acc2[r] + bb;
                hoS[lg * 4 + r][col] = 0.5f * vv * (1.f + erff(vv * 0.70710678118654752f));
            }
        }
        __syncthreads();
        {
            float v[4];
            #pragma unroll
            for (int k = 0; k < 4; k++) v[k] = hoS[crow][ccol + k];
            *(f32x4*)(outF + (size_t)(m0 + crow) * 128 + ccol) = *(f32x4*)v;
        }
    }
}

extern "C" void kernel_launch(void* const* d_in, const int* in_sizes, int n_in,
                              void* d_out, int out_size, void* d_ws, size_t ws_size,
                              hipStream_t stream) {
    const float* atom     = (const float*)d_in[0];
    const int*   esrc     = (const int*)d_in[1];
    const float* bond     = (const float*)d_in[3];
    const float* fc1_w    = (const float*)d_in[4];
    const float* fc1_b    = (const float*)d_in[5];
    const float* fc2_w    = (const float*)d_in[6];
    const float* fc2_b    = (const float*)d_in[7];
    const float* att_w    = (const float*)d_in[8];
    const float* att_b    = (const float*)d_in[9];
    const float* attend_w = (const float*)d_in[10];
    const float* attend_b = (const float*)d_in[11];
    const float* gih1     = (const float*)d_in[12];
    const float* ghh1     = (const float*)d_in[13];
    const float* bih1     = (const float*)d_in[14];
    const float* bhh1     = (const float*)d_in[15];
    const float* fc1v2_w  = (const float*)d_in[16];
    const float* fc1v2_b  = (const float*)d_in[17];
    const float* fc2v2_w  = (const float*)d_in[18];
    const float* fc2v2_b  = (const float*)d_in[19];
    const float* gih2     = (const float*)d_in[20];
    const float* ghh2     = (const float*)d_in[21];
    const float* bih2     = (const float*)d_in[22];
    const float* bhh2     = (const float*)d_in[23];
    const float* lin_w    = (const float*)d_in[24];
    const float* lin_b    = (const float*)d_in[25];

    char* wsb = (char*)d_ws;
    size_t off = 0;
    auto allocB = [&](size_t bytes) {
        size_t o = off; off = (off + bytes + 255) & ~(size_t)255; return o;
    };
    unsigned short* Bfc1   = (unsigned short*)(wsb + allocB(128 * 128 * 2));
    unsigned short* Batt   = (unsigned short*)(wsb + allocB(128 * 128 * 2));
    unsigned short* BW2a   = (unsigned short*)(wsb + allocB(128 * 128 * 2));
    unsigned short* BW2b   = (unsigned short*)(wsb + allocB(512 * 8 * 2));
    unsigned short* Bgih1  = (unsigned short*)(wsb + allocB(384 * 128 * 2));
    unsigned short* Bghh1  = (unsigned short*)(wsb + allocB(384 * 128 * 2));
    unsigned short* Bfc2v2 = (unsigned short*)(wsb + allocB(128 * 128 * 2));
    unsigned short* Bgih2  = (unsigned short*)(wsb + allocB(384 * 128 * 2));
    unsigned short* Bghh2  = (unsigned short*)(wsb + allocB(384 * 128 * 2));
    unsigned short* Blin   = (unsigned short*)(wsb + allocB(128 * 128 * 2));
    unsigned short* naBf   = (unsigned short*)(wsb + allocB((size_t)NN * 128 * 2));
    unsigned short* Ubf    = (unsigned short*)(wsb + allocB((size_t)NN * 128 * 2));
    unsigned short* aggBf  = (unsigned short*)(wsb + allocB((size_t)NN * 128 * 2));
    unsigned short* h1Bf   = (unsigned short*)(wsb + allocB((size_t)NN * 128 * 2));
    unsigned short* h2Bf   = (unsigned short*)(wsb + allocB((size_t)NN * 128 * 2));
    float* logits = (float*)(wsb + allocB((size_t)EE * 4));
    float* adst   = (float*)(wsb + allocB((size_t)NN * 4));
    float* aD     = (float*)(wsb + allocB((size_t)NN * 4));
    float* bS     = (float*)(wsb + allocB((size_t)NN * 4));
    (void)ws_size;

    float* out0 = (float*)d_out;
    float* as0  = out0 + (size_t)NN * 128;
    float* as1  = as0 + (size_t)NN * 128;
    float* as2  = as1 + (size_t)NN * 128;
    float* g0   = out0 + (size_t)4 * NN * 128;
    float* avg  = out0 + (size_t)5 * NN * 128;

    PackArgs pa;
    pa.d[0] = { fc1_w,    Bfc1,   128, 128, 0 };
    pa.d[1] = { attend_w, Batt,   128, 128, 0 };
    pa.d[2] = { fc2_w,    BW2a,   128, 144, 0 };
    pa.d[3] = { gih1,     Bgih1,  384, 128, 0 };
    pa.d[4] = { ghh1,     Bghh1,  384, 128, 0 };
    pa.d[5] = { fc2v2_w,  Bfc2v2, 128, 128, 0 };
    pa.d[6] = { gih2,     Bgih2,  384, 128, 0 };
    pa.d[7] = { ghh2,     Bghh2,  384, 128, 0 };
    pa.d[8] = { lin_w,    Blin,   128, 128, 0 };
    pa.d[9] = { fc2_w,    BW2b,   0,   0,   1 };
    k_pack<<<dim3(24, 10), 256, 0, stream>>>(pa);

    const int GB = NN / 16;   // 1250

    // ---- V1 ----
    k_v1_front<<<GB, 256, 0, stream>>>(atom, Bfc1, BW2a, fc1_b, fc2_b, att_w,
                                       g0, naBf, Ubf, adst);
    k_logits_v1<<<NN / 4, 256, 0, stream>>>(Ubf, esrc, bond, BW2b, att_w, att_b,
                                            adst, logits);
    k_agg<0, 0><<<GB, 256, 0, stream>>>(logits, nullptr, nullptr, nullptr, esrc, naBf, aggBf);
    k_agg<0, 1><<<GB, 256, 0, stream>>>(logits, nullptr, nullptr, nullptr, esrc, naBf, aggBf);
    k_gru<1, 0><<<GB, 512, 0, stream>>>(
        aggBf, Batt, attend_b,
        naBf, Bgih1, Bghh1, bih1, bhh1, g0, as0, h1Bf,
        fc1v2_w, aD, bS,
        nullptr, nullptr, nullptr, nullptr, nullptr, nullptr);

    // ---- V2 layer 2 ----
    k_agg<1, 0><<<GB, 256, 0, stream>>>(nullptr, aD, bS, fc1v2_b, esrc, h1Bf, aggBf);
    k_agg<1, 1><<<GB, 256, 0, stream>>>(nullptr, aD, bS, fc1v2_b, esrc, h1Bf, aggBf);
    k_gru<1, 0><<<GB, 512, 0, stream>>>(
        aggBf, Bfc2v2, fc2v2_b,
        h1Bf, Bgih2, Bghh2, bih2, bhh2, as0, as1, h2Bf,
        fc1v2_w, aD, bS,
        nullptr, nullptr, nullptr, nullptr, nullptr, nullptr);

    // ---- V2 layer 3 + final ----
    k_agg<1, 0><<<GB, 256, 0, stream>>>(nullptr, aD, bS, fc1v2_b, esrc, h2Bf, aggBf);
    k_agg<1, 1><<<GB, 256, 0, stream>>>(nullptr, aD, bS, fc1v2_b, esrc, h2Bf, aggBf);
    k_gru<0, 1><<<GB, 512, 0, stream>>>(
        aggBf, Bfc2v2, fc2v2_b,
        h2Bf, Bgih2, Bghh2, bih2, bhh2, as1, as2, nullptr,
        nullptr, nullptr, nullptr,
        as0, as1, Blin, lin_b, avg, out0);
}

// Round 8
// 149.030 us; speedup vs baseline: 1.1861x; 1.0134x over previous
//
#include <hip/hip_runtime.h>
#include <math.h>

#define NN 20000
#define EE 320000

using short8 = __attribute__((ext_vector_type(8))) short;
using f32x4  = __attribute__((ext_vector_type(4))) float;
using u16x4  = __attribute__((ext_vector_type(4))) unsigned short;

__device__ __forceinline__ unsigned short f2bf(float x) {
    union { float f; unsigned u; } v; v.f = x;
    unsigned r = (v.u + 0x7fffu + ((v.u >> 16) & 1u)) >> 16;
    return (unsigned short)r;
}
__device__ __forceinline__ float bf2f(unsigned short b) {
    union { unsigned u; float f; } v; v.u = ((unsigned)b) << 16;
    return v.f;
}
__device__ __forceinline__ float sigmoidf_(float x) { return 1.f / (1.f + __expf(-x)); }
__device__ __forceinline__ float tanhf_(float x) {
    float e = __expf(-2.f * x);
    return (1.f - e) / (1.f + e);
}
__device__ __forceinline__ float lrelu_(float x) { return x > 0.f ? x : 0.2f * x; }
__device__ __forceinline__ float elu_(float x) { return x > 0.f ? x : __expf(x) - 1.f; }

// ---------------- weight pack into MFMA B-fragment layout ----------------
struct PackDesc { const float* w; unsigned short* out; int O; int ldw; int mode; };
struct PackArgs { PackDesc d[10]; };

__global__ void k_pack(PackArgs args) {
    PackDesc d = args.d[blockIdx.y];
    int idx = blockIdx.x * 256 + threadIdx.x;
    if (d.mode == 1) {   // W2b: bond part of fc2_w, K=32 zero-padded
        if (idx >= 512) return;
        int t = idx >> 6, l = idx & 63;
        int lr = l & 15, lg = l >> 4;
        int ch = lr * 8 + t;
        short8 o;
        #pragma unroll
        for (int j = 0; j < 8; j++) {
            int k = lg * 8 + j;
            o[j] = (k < 16) ? (short)f2bf(d.w[(size_t)ch * 144 + 128 + k]) : (short)0;
        }
        *(short8*)(d.out + (size_t)idx * 8) = o;
        return;
    }
    int total = (d.O / 16) * 4 * 64;
    if (idx >= total) return;
    int l = idx & 63, rest = idx >> 6;
    int ko = rest & 3, no = rest >> 2;
    int row = no * 16 + (l & 15);
    int col0 = ko * 32 + ((l >> 4) * 8);
    const float* src = d.w + (size_t)row * d.ldw + col0;
    unsigned short o[8];
    #pragma unroll
    for (int j = 0; j < 8; j++) o[j] = f2bf(src[j]);
    #pragma unroll
    for (int j = 0; j < 8; j++) d.out[(size_t)idx * 8 + j] = o[j];
}

// ---------------- V1 front ----------------
__global__ __launch_bounds__(256) void k_v1_front(
    const float* __restrict__ atom,
    const unsigned short* __restrict__ Bfc1, const unsigned short* __restrict__ BW2a,
    const float* __restrict__ fc1_b, const float* __restrict__ fc2_b,
    const float* __restrict__ attw,
    float* __restrict__ g0, unsigned short* __restrict__ naBf,
    unsigned short* __restrict__ Ubf, float* __restrict__ adst)
{
    __shared__ float Xs[16][132];
    __shared__ unsigned short Ys2[16 * 128];
    const int tid = threadIdx.x, l = tid & 63, w = tid >> 6;
    const int lr = l & 15, lg = l >> 4;
    const int m0 = blockIdx.x * 16;

    f32x4 acc1[2] = {}, accU[2] = {};
    #pragma unroll
    for (int ko = 0; ko < 4; ko++) {
        const f32x4* ap = (const f32x4*)(atom + (size_t)(m0 + lr) * 128 + ko * 32 + lg * 8);
        f32x4 a0 = ap[0], a1 = ap[1];
        short8 af;
        #pragma unroll
        for (int j = 0; j < 4; j++) { af[j] = (short)f2bf(a0[j]); af[4 + j] = (short)f2bf(a1[j]); }
        #pragma unroll
        for (int i = 0; i < 2; i++) {
            int t = w * 2 + i;
            short8 b1 = *(const short8*)(Bfc1 + ((size_t)(t * 4 + ko) * 64 + l) * 8);
            acc1[i] = __builtin_amdgcn_mfma_f32_16x16x32_bf16(af, b1, acc1[i], 0, 0, 0);
            short8 bu = *(const short8*)(BW2a + ((size_t)(t * 4 + ko) * 64 + l) * 8);
            accU[i] = __builtin_amdgcn_mfma_f32_16x16x32_bf16(af, bu, accU[i], 0, 0, 0);
        }
    }
    #pragma unroll
    for (int i = 0; i < 2; i++) {
        int col = (w * 2 + i) * 16 + lr;
        float b1v = fc1_b[col], bUv = fc2_b[col];
        #pragma unroll
        for (int r = 0; r < 4; r++) {
            int row = lg * 4 + r;
            float v = lrelu_(acc1[i][r] + b1v);
            Xs[row][col] = v;
            Ys2[row * 128 + col] = f2bf(accU[i][r] + bUv);
        }
    }
    __syncthreads();
    *(short8*)(Ubf + (size_t)m0 * 128 + tid * 8) = *(const short8*)(Ys2 + tid * 8);
    {
        int row = tid >> 4, q = tid & 15;
        short8 tmp;
        float p = 0.f;
        float vv[8];
        #pragma unroll
        for (int j = 0; j < 8; j++) {
            float x = Xs[row][q * 8 + j];
            vv[j] = x;
            tmp[j] = (short)f2bf(x);
            p = fmaf(x, attw[q * 8 + j], p);
        }
        *(f32x4*)(g0 + (size_t)(m0 + row) * 128 + q * 8) = *(f32x4*)vv;
        *(f32x4*)(g0 + (size_t)(m0 + row) * 128 + q * 8 + 4) = *(f32x4*)(vv + 4);
        *(short8*)(naBf + (size_t)(m0 + row) * 128 + q * 8) = tmp;
        #pragma unroll
        for (int m = 1; m <= 8; m <<= 1) p += __shfl_xor(p, m, 16);
        if (q == 0) adst[m0 + row] = p;
    }
}

// ---------------- V1 edge logits ----------------
__global__ __launch_bounds__(256) void k_logits_v1(
    const unsigned short* __restrict__ U, const int* __restrict__ esrc,
    const float* __restrict__ bond, const unsigned short* __restrict__ BW2b,
    const float* __restrict__ attw, const float* __restrict__ attb1,
    const float* __restrict__ adst, float* __restrict__ logits)
{
    const int tid = threadIdx.x, l = tid & 63, w = tid >> 6;
    const int lr = l & 15, lg = l >> 4;
    const int n = blockIdx.x * 4 + w;
    const int e0 = n * 16;

    short8 af = {};
    if (lg < 2) {
        const f32x4* bp = (const f32x4*)(bond + (size_t)(e0 + lr) * 16 + lg * 8);
        f32x4 b0 = bp[0], b1 = bp[1];
        #pragma unroll
        for (int j = 0; j < 4; j++) { af[j] = (short)f2bf(b0[j]); af[4 + j] = (short)f2bf(b1[j]); }
    }
    f32x4 c[8];
    #pragma unroll
    for (int t = 0; t < 8; t++) {
        short8 bf = *(const short8*)(BW2b + (size_t)(t * 64 + l) * 8);
        f32x4 z = {};
        c[t] = __builtin_amdgcn_mfma_f32_16x16x32_bf16(af, bf, z, 0, 0, 0);
    }
    float aw[8];
    #pragma unroll
    for (int t = 0; t < 8; t++) aw[t] = attw[128 + lr * 8 + t];

    float s[4];
    #pragma unroll
    for (int r = 0; r < 4; r++) {
        int e = e0 + lg * 4 + r;
        int src = esrc[e];
        short8 u = *(const short8*)(U + (size_t)src * 128 + lr * 8);
        float a0 = 0.f;
        #pragma unroll
        for (int t = 0; t < 8; t++)
            a0 = fmaf(aw[t], lrelu_(c[t][r] + bf2f((unsigned short)u[t])), a0);
        s[r] = a0;
    }
    #pragma unroll
    for (int mk = 1; mk <= 8; mk <<= 1)
        #pragma unroll
        for (int r = 0; r < 4; r++) s[r] += __shfl_xor(s[r], mk, 16);
    if (lr == 0) {
        float anode = adst[n], ab = attb1[0];
        f32x4 o;
        #pragma unroll
        for (int r = 0; r < 4; r++) o[r] = lrelu_(anode + ab + s[r]);
        *(f32x4*)(logits + e0 + lg * 4) = o;
    }
}

// ---------------- aggregation pass: softmax + gather HALF of channels -------------
template<int MODE, int HALF>
__global__ __launch_bounds__(256) void k_agg(
    const float* __restrict__ logits, const float* __restrict__ aD,
    const float* __restrict__ bS, const float* __restrict__ b1,
    const int* __restrict__ esrc, const unsigned short* __restrict__ V,
    unsigned short* __restrict__ agg)
{
    const int tid = threadIdx.x;
    const int node = blockIdx.x * 16 + (tid >> 4);
    const int q = tid & 15;
    const int e = node * 16 + q;
    const int src = esrc[e];
    float lgt;
    if (MODE == 0) lgt = logits[e];
    else           lgt = lrelu_(aD[node] + bS[src] + b1[0]);
    float mx = lgt;
    #pragma unroll
    for (int mk = 1; mk <= 8; mk <<= 1) mx = fmaxf(mx, __shfl_xor(mx, mk, 16));
    float ex = __expf(lgt - mx);
    float den = ex;
    #pragma unroll
    for (int mk = 1; mk <= 8; mk <<= 1) den += __shfl_xor(den, mk, 16);
    float wq = ex / den;
    float s0 = 0.f, s1 = 0.f, s2 = 0.f, s3 = 0.f;
    #pragma unroll
    for (int i = 0; i < 16; i++) {
        float wi = __shfl(wq, i, 16);
        int si = __shfl(src, i, 16);
        u16x4 v = *(const u16x4*)(V + (size_t)si * 128 + HALF * 64 + q * 4);
        s0 = fmaf(wi, bf2f(v[0]), s0);
        s1 = fmaf(wi, bf2f(v[1]), s1);
        s2 = fmaf(wi, bf2f(v[2]), s2);
        s3 = fmaf(wi, bf2f(v[3]), s3);
    }
    u16x4 o;
    o[0] = f2bf(s0); o[1] = f2bf(s1); o[2] = f2bf(s2); o[3] = f2bf(s3);
    *(u16x4*)(agg + (size_t)node * 128 + HALF * 64 + q * 4) = o;
}

// ---------------- GRU: 32-row blocks, 512 threads (8 waves) ----------------
// Wave w owns channel-tile w for BOTH 16-row subtiles: tiles w (r), w+8 (z), w+16 (n).
// h A-fragments converted from LDS-staged f32 hprev (no global hBf reads).
template<int FRONT, int FINAL>
__global__ __launch_bounds__(512, 4) void k_gru(
    const unsigned short* __restrict__ agg,
    const unsigned short* __restrict__ Bpre, const float* __restrict__ bpre,
    const unsigned short* __restrict__ Bih, const unsigned short* __restrict__ Bhh,
    const float* __restrict__ bih, const float* __restrict__ bhh,
    const float* __restrict__ hprevF, float* __restrict__ houtF,
    unsigned short* __restrict__ houtBf,
    const float* __restrict__ w2att, float* __restrict__ aDOut, float* __restrict__ bSOut,
    const float* __restrict__ as0, const float* __restrict__ as1,
    const unsigned short* __restrict__ Blin, const float* __restrict__ linb,
    float* __restrict__ avgOut, float* __restrict__ outF)
{
    __shared__ unsigned short ctxS[32][136];
    __shared__ float hoS[32][132];
    const int tid = threadIdx.x, l = tid & 63, w = tid >> 6;   // w in 0..7
    const int lr = l & 15, lg = l >> 4;
    const int m0 = blockIdx.x * 32;
    const int srow = tid >> 4, sc0 = (tid & 15) * 8;           // 32B/thread staging map

    // stage hprev (coalesced) into hoS
    {
        const f32x4* hp = (const f32x4*)(hprevF + (size_t)(m0 + srow) * 128 + sc0);
        *(f32x4*)&hoS[srow][sc0] = hp[0];
        *(f32x4*)&hoS[srow][sc0 + 4] = hp[1];
    }

    // ---- pre-GEMM: ctx = elu(agg @ Wpre^T + b), wave w -> col-tile w, 2 row-tiles ----
    f32x4 accp[2] = {};
    #pragma unroll
    for (int ko = 0; ko < 4; ko++) {
        short8 bf = *(const short8*)(Bpre + ((size_t)(w * 4 + ko) * 64 + l) * 8);
        #pragma unroll
        for (int rt = 0; rt < 2; rt++) {
            short8 af = *(const short8*)(agg + (size_t)(m0 + rt * 16 + lr) * 128 + ko * 32 + lg * 8);
            accp[rt] = __builtin_amdgcn_mfma_f32_16x16x32_bf16(af, bf, accp[rt], 0, 0, 0);
        }
    }
    {
        const int col = w * 16 + lr;
        const float bb = bpre[col];
        #pragma unroll
        for (int rt = 0; rt < 2; rt++)
            #pragma unroll
            for (int r = 0; r < 4; r++)
                ctxS[rt * 16 + lg * 4 + r][col] = f2bf(elu_(accp[rt][r] + bb));
    }
    __syncthreads();

    // ---- GRU GEMMs: 12 accumulators per wave (2 row-tiles x 3 gates x {ih,hh}) ----
    f32x4 ai[2][3] = {}, ah[2][3] = {};
    #pragma unroll
    for (int ko = 0; ko < 4; ko++) {
        short8 afc[2], afh[2];
        #pragma unroll
        for (int rt = 0; rt < 2; rt++) {
            afc[rt] = *(const short8*)&ctxS[rt * 16 + lr][ko * 32 + lg * 8];
            const float* hp = &hoS[rt * 16 + lr][ko * 32 + lg * 8];
            short8 t;
            #pragma unroll
            for (int j = 0; j < 8; j++) t[j] = (short)f2bf(hp[j]);
            afh[rt] = t;
        }
        #pragma unroll
        for (int g = 0; g < 3; g++) {
            short8 bi = *(const short8*)(Bih + ((size_t)((w + 8 * g) * 4 + ko) * 64 + l) * 8);
            #pragma unroll
            for (int rt = 0; rt < 2; rt++)
                ai[rt][g] = __builtin_amdgcn_mfma_f32_16x16x32_bf16(afc[rt], bi, ai[rt][g], 0, 0, 0);
            short8 bh = *(const short8*)(Bhh + ((size_t)((w + 8 * g) * 4 + ko) * 64 + l) * 8);
            #pragma unroll
            for (int rt = 0; rt < 2; rt++)
                ah[rt][g] = __builtin_amdgcn_mfma_f32_16x16x32_bf16(afh[rt], bh, ah[rt][g], 0, 0, 0);
        }
    }
    __syncthreads();   // all hoS reads (h A-frags) done before gate overwrites

    // ---- gates: channel c = w*16+lr, rows rt*16+lg*4+r (unique per thread) ----
    {
        const int c = w * 16 + lr;
        const float br = bih[c] + bhh[c];
        const float bz = bih[c + 128] + bhh[c + 128];
        const float bin_ = bih[c + 256];
        const float bhn = bhh[c + 256];
        #pragma unroll
        for (int rt = 0; rt < 2; rt++)
            #pragma unroll
            for (int r = 0; r < 4; r++) {
                const int lrow = rt * 16 + lg * 4 + r;
                float rg = sigmoidf_(ai[rt][0][r] + ah[rt][0][r] + br);
                float zg = sigmoidf_(ai[rt][1][r] + ah[rt][1][r] + bz);
                float ng = tanhf_(ai[rt][2][r] + bin_ + rg * (ah[rt][2][r] + bhn));
                float hp = hoS[lrow][c];
                hoS[lrow][c] = fmaf(zg, hp - ng, ng);
            }
    }
    __syncthreads();

    // ---- coalesced h writes ----
    {
        float v[8];
        #pragma unroll
        for (int k = 0; k < 8; k++) v[k] = hoS[srow][sc0 + k];
        f32x4* dst = (f32x4*)(houtF + (size_t)(m0 + srow) * 128 + sc0);
        dst[0] = *(f32x4*)v;
        dst[1] = *(f32x4*)(v + 4);
        if (FINAL == 0) {
            short8 p;
            #pragma unroll
            for (int k = 0; k < 8; k++) p[k] = (short)f2bf(v[k]);
            *(short8*)(houtBf + (size_t)(m0 + srow) * 128 + sc0) = p;
        }
    }

    if (FRONT) {
        int row = tid >> 4, q = tid & 15;
        float pa = 0.f, pb = 0.f;
        #pragma unroll
        for (int j = 0; j < 8; j++) {
            float x = hoS[row][q * 8 + j];
            pa = fmaf(x, w2att[q * 8 + j], pa);
            pb = fmaf(x, w2att[128 + q * 8 + j], pb);
        }
        #pragma unroll
        for (int m = 1; m <= 8; m <<= 1) {
            pa += __shfl_xor(pa, m, 16);
            pb += __shfl_xor(pb, m, 16);
        }
        if (q == 0) { aDOut[m0 + row] = pa; bSOut[m0 + row] = pb; }
    }

    if (FINAL) {
        // avg (coalesced) -> avgOut + ctxS(bf16)
        {
            const f32x4* p0 = (const f32x4*)(as0 + (size_t)(m0 + srow) * 128 + sc0);
            const f32x4* p1 = (const f32x4*)(as1 + (size_t)(m0 + srow) * 128 + sc0);
            f32x4* pav = (f32x4*)(avgOut + (size_t)(m0 + srow) * 128 + sc0);
            #pragma unroll
            for (int k = 0; k < 2; k++) {
                f32x4 x0 = p0[k], x1 = p1[k];
                f32x4 av;
                #pragma unroll
                for (int j = 0; j < 4; j++)
                    av[j] = (x0[j] + x1[j] + hoS[srow][sc0 + k * 4 + j]) * (1.f / 3.f);
                pav[k] = av;
                #pragma unroll
                for (int j = 0; j < 4; j++) ctxS[srow][sc0 + k * 4 + j] = f2bf(av[j]);
            }
        }
        __syncthreads();
        // lin GEMM: wave w -> col-tile w, 2 row-tiles
        f32x4 acc2[2] = {};
        #pragma unroll
        for (int ko = 0; ko < 4; ko++) {
            short8 bf = *(const short8*)(Blin + ((size_t)(w * 4 + ko) * 64 + l) * 8);
            #pragma unroll
            for (int rt = 0; rt < 2; rt++) {
                short8 af = *(const short8*)&ctxS[rt * 16 + lr][ko * 32 + lg * 8];
                acc2[rt] = __builtin_amdgcn_mfma_f32_16x16x32_bf16(af, bf, acc2[rt], 0, 0, 0);
            }
        }
        {
            const int col = w * 16 + lr;
            const float bb = linb[col];
            #pragma unroll
            for (int rt = 0; rt < 2; rt++)
                #pragma unroll
                for (int r = 0; r < 4; r++) {
                    float vv = acc2[rt][r] + bb;
                    hoS[rt * 16 + lg * 4 + r][col] =
                        0.5f * vv * (1.f + erff(vv * 0.70710678118654752f));
                }
        }
        __syncthreads();
        {
            float v[8];
            #pragma unroll
            for (int k = 0; k < 8; k++) v[k] = hoS[srow][sc0 + k];
            f32x4* dst = (f32x4*)(outF + (size_t)(m0 + srow) * 128 + sc0);
            dst[0] = *(f32x4*)v;
            dst[1] = *(f32x4*)(v + 4);
        }
    }
}

extern "C" void kernel_launch(void* const* d_in, const int* in_sizes, int n_in,
                              void* d_out, int out_size, void* d_ws, size_t ws_size,
                              hipStream_t stream) {
    const float* atom     = (const float*)d_in[0];
    const int*   esrc     = (const int*)d_in[1];
    const float* bond     = (const float*)d_in[3];
    const float* fc1_w    = (const float*)d_in[4];
    const float* fc1_b    = (const float*)d_in[5];
    const float* fc2_w    = (const float*)d_in[6];
    const float* fc2_b    = (const float*)d_in[7];
    const float* att_w    = (const float*)d_in[8];
    const float* att_b    = (const float*)d_in[9];
    const float* attend_w = (const float*)d_in[10];
    const float* attend_b = (const float*)d_in[11];
    const float* gih1     = (const float*)d_in[12];
    const float* ghh1     = (const float*)d_in[13];
    const float* bih1     = (const float*)d_in[14];
    const float* bhh1     = (const float*)d_in[15];
    const float* fc1v2_w  = (const float*)d_in[16];
    const float* fc1v2_b  = (const float*)d_in[17];
    const float* fc2v2_w  = (const float*)d_in[18];
    const float* fc2v2_b  = (const float*)d_in[19];
    const float* gih2     = (const float*)d_in[20];
    const float* ghh2     = (const float*)d_in[21];
    const float* bih2     = (const float*)d_in[22];
    const float* bhh2     = (const float*)d_in[23];
    const float* lin_w    = (const float*)d_in[24];
    const float* lin_b    = (const float*)d_in[25];

    char* wsb = (char*)d_ws;
    size_t off = 0;
    auto allocB = [&](size_t bytes) {
        size_t o = off; off = (off + bytes + 255) & ~(size_t)255; return o;
    };
    unsigned short* Bfc1   = (unsigned short*)(wsb + allocB(128 * 128 * 2));
    unsigned short* Batt   = (unsigned short*)(wsb + allocB(128 * 128 * 2));
    unsigned short* BW2a   = (unsigned short*)(wsb + allocB(128 * 128 * 2));
    unsigned short* BW2b   = (unsigned short*)(wsb + allocB(512 * 8 * 2));
    unsigned short* Bgih1  = (unsigned short*)(wsb + allocB(384 * 128 * 2));
    unsigned short* Bghh1  = (unsigned short*)(wsb + allocB(384 * 128 * 2));
    unsigned short* Bfc2v2 = (unsigned short*)(wsb + allocB(128 * 128 * 2));
    unsigned short* Bgih2  = (unsigned short*)(wsb + allocB(384 * 128 * 2));
    unsigned short* Bghh2  = (unsigned short*)(wsb + allocB(384 * 128 * 2));
    unsigned short* Blin   = (unsigned short*)(wsb + allocB(128 * 128 * 2));
    unsigned short* naBf   = (unsigned short*)(wsb + allocB((size_t)NN * 128 * 2));
    unsigned short* Ubf    = (unsigned short*)(wsb + allocB((size_t)NN * 128 * 2));
    unsigned short* aggBf  = (unsigned short*)(wsb + allocB((size_t)NN * 128 * 2));
    unsigned short* h1Bf   = (unsigned short*)(wsb + allocB((size_t)NN * 128 * 2));
    unsigned short* h2Bf   = (unsigned short*)(wsb + allocB((size_t)NN * 128 * 2));
    float* logits = (float*)(wsb + allocB((size_t)EE * 4));
    float* adst   = (float*)(wsb + allocB((size_t)NN * 4));
    float* aD     = (float*)(wsb + allocB((size_t)NN * 4));
    float* bS     = (float*)(wsb + allocB((size_t)NN * 4));
    (void)ws_size;

    float* out0 = (float*)d_out;
    float* as0  = out0 + (size_t)NN * 128;
    float* as1  = as0 + (size_t)NN * 128;
    float* as2  = as1 + (size_t)NN * 128;
    float* g0   = out0 + (size_t)4 * NN * 128;
    float* avg  = out0 + (size_t)5 * NN * 128;

    PackArgs pa;
    pa.d[0] = { fc1_w,    Bfc1,   128, 128, 0 };
    pa.d[1] = { attend_w, Batt,   128, 128, 0 };
    pa.d[2] = { fc2_w,    BW2a,   128, 144, 0 };
    pa.d[3] = { gih1,     Bgih1,  384, 128, 0 };
    pa.d[4] = { ghh1,     Bghh1,  384, 128, 0 };
    pa.d[5] = { fc2v2_w,  Bfc2v2, 128, 128, 0 };
    pa.d[6] = { gih2,     Bgih2,  384, 128, 0 };
    pa.d[7] = { ghh2,     Bghh2,  384, 128, 0 };
    pa.d[8] = { lin_w,    Blin,   128, 128, 0 };
    pa.d[9] = { fc2_w,    BW2b,   0,   0,   1 };
    k_pack<<<dim3(24, 10), 256, 0, stream>>>(pa);

    const int GB = NN / 16;     // 1250
    const int GB32 = NN / 32;   // 625

    // ---- V1 ----
    k_v1_front<<<GB, 256, 0, stream>>>(atom, Bfc1, BW2a, fc1_b, fc2_b, att_w,
                                       g0, naBf, Ubf, adst);
    k_logits_v1<<<NN / 4, 256, 0, stream>>>(Ubf, esrc, bond, BW2b, att_w, att_b,
                                            adst, logits);
    k_agg<0, 0><<<GB, 256, 0, stream>>>(logits, nullptr, nullptr, nullptr, esrc, naBf, aggBf);
    k_agg<0, 1><<<GB, 256, 0, stream>>>(logits, nullptr, nullptr, nullptr, esrc, naBf, aggBf);
    k_gru<1, 0><<<GB32, 512, 0, stream>>>(
        aggBf, Batt, attend_b,
        Bgih1, Bghh1, bih1, bhh1, g0, as0, h1Bf,
        fc1v2_w, aD, bS,
        nullptr, nullptr, nullptr, nullptr, nullptr, nullptr);

    // ---- V2 layer 2 ----
    k_agg<1, 0><<<GB, 256, 0, stream>>>(nullptr, aD, bS, fc1v2_b, esrc, h1Bf, aggBf);
    k_agg<1, 1><<<GB, 256, 0, stream>>>(nullptr, aD, bS, fc1v2_b, esrc, h1Bf, aggBf);
    k_gru<1, 0><<<GB32, 512, 0, stream>>>(
        aggBf, Bfc2v2, fc2v2_b,
        Bgih2, Bghh2, bih2, bhh2, as0, as1, h2Bf,
        fc1v2_w, aD, bS,
        nullptr, nullptr, nullptr, nullptr, nullptr, nullptr);

    // ---- V2 layer 3 + final ----
    k_agg<1, 0><<<GB, 256, 0, stream>>>(nullptr, aD, bS, fc1v2_b, esrc, h2Bf, aggBf);
    k_agg<1, 1><<<GB, 256, 0, stream>>>(nullptr, aD, bS, fc1v2_b, esrc, h2Bf, aggBf);
    k_gru<0, 1><<<GB32, 512, 0, stream>>>(
        aggBf, Bfc2v2, fc2v2_b,
        Bgih2, Bghh2, bih2, bhh2, as1, as2, nullptr,
        nullptr, nullptr, nullptr,
        as0, as1, Blin, lin_b, avg, out0);
}

// Round 9
// 142.725 us; speedup vs baseline: 1.2385x; 1.0442x over previous
//
#include <hip/hip_runtime.h>
#include <math.h>

#define NN 20000
#define EE 320000

using short8 = __attribute__((ext_vector_type(8))) short;
using f32x4  = __attribute__((ext_vector_type(4))) float;
using u16x4  = __attribute__((ext_vector_type(4))) unsigned short;

__device__ __forceinline__ unsigned short f2bf(float x) {
    union { float f; unsigned u; } v; v.f = x;
    unsigned r = (v.u + 0x7fffu + ((v.u >> 16) & 1u)) >> 16;
    return (unsigned short)r;
}
__device__ __forceinline__ float bf2f(unsigned short b) {
    union { unsigned u; float f; } v; v.u = ((unsigned)b) << 16;
    return v.f;
}
__device__ __forceinline__ float sigmoidf_(float x) { return 1.f / (1.f + __expf(-x)); }
__device__ __forceinline__ float tanhf_(float x) {
    float e = __expf(-2.f * x);
    return (1.f - e) / (1.f + e);
}
__device__ __forceinline__ float lrelu_(float x) { return x > 0.f ? x : 0.2f * x; }
__device__ __forceinline__ float elu_(float x) { return x > 0.f ? x : __expf(x) - 1.f; }

// ---------------- weight pack into MFMA B-fragment layout ----------------
struct PackDesc { const float* w; unsigned short* out; int O; int ldw; int mode; };
struct PackArgs { PackDesc d[10]; };

__global__ void k_pack(PackArgs args) {
    PackDesc d = args.d[blockIdx.y];
    int idx = blockIdx.x * 256 + threadIdx.x;
    if (d.mode == 1) {   // W2b: bond part of fc2_w, K=32 zero-padded
        if (idx >= 512) return;
        int t = idx >> 6, l = idx & 63;
        int lr = l & 15, lg = l >> 4;
        int ch = lr * 8 + t;
        short8 o;
        #pragma unroll
        for (int j = 0; j < 8; j++) {
            int k = lg * 8 + j;
            o[j] = (k < 16) ? (short)f2bf(d.w[(size_t)ch * 144 + 128 + k]) : (short)0;
        }
        *(short8*)(d.out + (size_t)idx * 8) = o;
        return;
    }
    int total = (d.O / 16) * 4 * 64;
    if (idx >= total) return;
    int l = idx & 63, rest = idx >> 6;
    int ko = rest & 3, no = rest >> 2;
    int row = no * 16 + (l & 15);
    int col0 = ko * 32 + ((l >> 4) * 8);
    const float* src = d.w + (size_t)row * d.ldw + col0;
    unsigned short o[8];
    #pragma unroll
    for (int j = 0; j < 8; j++) o[j] = f2bf(src[j]);
    #pragma unroll
    for (int j = 0; j < 8; j++) d.out[(size_t)idx * 8 + j] = o[j];
}

// ---------------- V1 front ----------------
__global__ __launch_bounds__(256) void k_v1_front(
    const float* __restrict__ atom,
    const unsigned short* __restrict__ Bfc1, const unsigned short* __restrict__ BW2a,
    const float* __restrict__ fc1_b, const float* __restrict__ fc2_b,
    const float* __restrict__ attw,
    float* __restrict__ g0, unsigned short* __restrict__ naBf,
    unsigned short* __restrict__ Ubf, float* __restrict__ adst)
{
    __shared__ float Xs[16][132];
    __shared__ unsigned short Ys2[16 * 128];
    const int tid = threadIdx.x, l = tid & 63, w = tid >> 6;
    const int lr = l & 15, lg = l >> 4;
    const int m0 = blockIdx.x * 16;

    f32x4 acc1[2] = {}, accU[2] = {};
    #pragma unroll
    for (int ko = 0; ko < 4; ko++) {
        const f32x4* ap = (const f32x4*)(atom + (size_t)(m0 + lr) * 128 + ko * 32 + lg * 8);
        f32x4 a0 = ap[0], a1 = ap[1];
        short8 af;
        #pragma unroll
        for (int j = 0; j < 4; j++) { af[j] = (short)f2bf(a0[j]); af[4 + j] = (short)f2bf(a1[j]); }
        #pragma unroll
        for (int i = 0; i < 2; i++) {
            int t = w * 2 + i;
            short8 b1 = *(const short8*)(Bfc1 + ((size_t)(t * 4 + ko) * 64 + l) * 8);
            acc1[i] = __builtin_amdgcn_mfma_f32_16x16x32_bf16(af, b1, acc1[i], 0, 0, 0);
            short8 bu = *(const short8*)(BW2a + ((size_t)(t * 4 + ko) * 64 + l) * 8);
            accU[i] = __builtin_amdgcn_mfma_f32_16x16x32_bf16(af, bu, accU[i], 0, 0, 0);
        }
    }
    #pragma unroll
    for (int i = 0; i < 2; i++) {
        int col = (w * 2 + i) * 16 + lr;
        float b1v = fc1_b[col], bUv = fc2_b[col];
        #pragma unroll
        for (int r = 0; r < 4; r++) {
            int row = lg * 4 + r;
            float v = lrelu_(acc1[i][r] + b1v);
            Xs[row][col] = v;
            Ys2[row * 128 + col] = f2bf(accU[i][r] + bUv);
        }
    }
    __syncthreads();
    *(short8*)(Ubf + (size_t)m0 * 128 + tid * 8) = *(const short8*)(Ys2 + tid * 8);
    {
        int row = tid >> 4, q = tid & 15;
        short8 tmp;
        float p = 0.f;
        float vv[8];
        #pragma unroll
        for (int j = 0; j < 8; j++) {
            float x = Xs[row][q * 8 + j];
            vv[j] = x;
            tmp[j] = (short)f2bf(x);
            p = fmaf(x, attw[q * 8 + j], p);
        }
        *(f32x4*)(g0 + (size_t)(m0 + row) * 128 + q * 8) = *(f32x4*)vv;
        *(f32x4*)(g0 + (size_t)(m0 + row) * 128 + q * 8 + 4) = *(f32x4*)(vv + 4);
        *(short8*)(naBf + (size_t)(m0 + row) * 128 + q * 8) = tmp;
        #pragma unroll
        for (int m = 1; m <= 8; m <<= 1) p += __shfl_xor(p, m, 16);
        if (q == 0) adst[m0 + row] = p;
    }
}

// ---------------- V1 edge logits ----------------
__global__ __launch_bounds__(256) void k_logits_v1(
    const unsigned short* __restrict__ U, const int* __restrict__ esrc,
    const float* __restrict__ bond, const unsigned short* __restrict__ BW2b,
    const float* __restrict__ attw, const float* __restrict__ attb1,
    const float* __restrict__ adst, float* __restrict__ logits)
{
    const int tid = threadIdx.x, l = tid & 63, w = tid >> 6;
    const int lr = l & 15, lg = l >> 4;
    const int n = blockIdx.x * 4 + w;
    const int e0 = n * 16;

    short8 af = {};
    if (lg < 2) {
        const f32x4* bp = (const f32x4*)(bond + (size_t)(e0 + lr) * 16 + lg * 8);
        f32x4 b0 = bp[0], b1 = bp[1];
        #pragma unroll
        for (int j = 0; j < 4; j++) { af[j] = (short)f2bf(b0[j]); af[4 + j] = (short)f2bf(b1[j]); }
    }
    f32x4 c[8];
    #pragma unroll
    for (int t = 0; t < 8; t++) {
        short8 bf = *(const short8*)(BW2b + (size_t)(t * 64 + l) * 8);
        f32x4 z = {};
        c[t] = __builtin_amdgcn_mfma_f32_16x16x32_bf16(af, bf, z, 0, 0, 0);
    }
    float aw[8];
    #pragma unroll
    for (int t = 0; t < 8; t++) aw[t] = attw[128 + lr * 8 + t];

    float s[4];
    #pragma unroll
    for (int r = 0; r < 4; r++) {
        int e = e0 + lg * 4 + r;
        int src = esrc[e];
        short8 u = *(const short8*)(U + (size_t)src * 128 + lr * 8);
        float a0 = 0.f;
        #pragma unroll
        for (int t = 0; t < 8; t++)
            a0 = fmaf(aw[t], lrelu_(c[t][r] + bf2f((unsigned short)u[t])), a0);
        s[r] = a0;
    }
    #pragma unroll
    for (int mk = 1; mk <= 8; mk <<= 1)
        #pragma unroll
        for (int r = 0; r < 4; r++) s[r] += __shfl_xor(s[r], mk, 16);
    if (lr == 0) {
        float anode = adst[n], ab = attb1[0];
        f32x4 o;
        #pragma unroll
        for (int r = 0; r < 4; r++) o[r] = lrelu_(anode + ab + s[r]);
        *(f32x4*)(logits + e0 + lg * 4) = o;
    }
}

// ---------------- aggregation: softmax once + gather BOTH channel halves ----------
// MODE 0: logits from buffer (V1). MODE 1: inline logits aD[dst]+bS[src]+b (V2).
template<int MODE>
__global__ __launch_bounds__(256) void k_agg(
    const float* __restrict__ logits, const float* __restrict__ aD,
    const float* __restrict__ bS, const float* __restrict__ b1,
    const int* __restrict__ esrc, const unsigned short* __restrict__ V,
    unsigned short* __restrict__ agg)
{
    const int tid = threadIdx.x;
    const int node = blockIdx.x * 16 + (tid >> 4);
    const int q = tid & 15;
    const int e = node * 16 + q;
    const int src = esrc[e];
    float lgt;
    if (MODE == 0) lgt = logits[e];
    else           lgt = lrelu_(aD[node] + bS[src] + b1[0]);
    float mx = lgt;
    #pragma unroll
    for (int mk = 1; mk <= 8; mk <<= 1) mx = fmaxf(mx, __shfl_xor(mx, mk, 16));
    float ex = __expf(lgt - mx);
    float den = ex;
    #pragma unroll
    for (int mk = 1; mk <= 8; mk <<= 1) den += __shfl_xor(den, mk, 16);
    float wq = ex / den;
    float s[8] = {};
    #pragma unroll
    for (int i = 0; i < 16; i++) {
        float wi = __shfl(wq, i, 16);
        int si = __shfl(src, i, 16);
        const unsigned short* vp = V + (size_t)si * 128 + q * 4;
        u16x4 v0 = *(const u16x4*)vp;
        #pragma unroll
        for (int j = 0; j < 4; j++) s[j] = fmaf(wi, bf2f(v0[j]), s[j]);
        u16x4 v1 = *(const u16x4*)(vp + 64);
        #pragma unroll
        for (int j = 0; j < 4; j++) s[4 + j] = fmaf(wi, bf2f(v1[j]), s[4 + j]);
    }
    u16x4 o0, o1;
    #pragma unroll
    for (int j = 0; j < 4; j++) { o0[j] = f2bf(s[j]); o1[j] = f2bf(s[4 + j]); }
    *(u16x4*)(agg + (size_t)node * 128 + q * 4) = o0;
    *(u16x4*)(agg + (size_t)node * 128 + 64 + q * 4) = o1;
}

// ---------------- GRU: 32-row blocks, 512 threads (8 waves), bf16 h-prev ----------
// Wave w owns channel-tile w: output tiles w (r), w+8 (z), w+16 (n) for ih & hh.
template<int FRONT, int FINAL>
__global__ __launch_bounds__(512, 4) void k_gru(
    const unsigned short* __restrict__ agg,
    const unsigned short* __restrict__ Bpre, const float* __restrict__ bpre,
    const unsigned short* __restrict__ Bih, const unsigned short* __restrict__ Bhh,
    const float* __restrict__ bih, const float* __restrict__ bhh,
    const unsigned short* __restrict__ hprevBf, float* __restrict__ houtF,
    unsigned short* __restrict__ houtBf,
    const float* __restrict__ w2att, float* __restrict__ aDOut, float* __restrict__ bSOut,
    const float* __restrict__ as0, const float* __restrict__ as1,
    const unsigned short* __restrict__ Blin, const float* __restrict__ linb,
    float* __restrict__ avgOut, float* __restrict__ outF)
{
    __shared__ unsigned short ctxS[32][136];
    __shared__ unsigned short hpS[32][136];
    __shared__ float hoS[32][132];
    const int tid = threadIdx.x, l = tid & 63, w = tid >> 6;   // w in 0..7
    const int lr = l & 15, lg = l >> 4;
    const int m0 = blockIdx.x * 32;
    const int srow = tid >> 4, sc0 = (tid & 15) * 8;           // 16B/thread staging map

    // stage bf16 hprev (coalesced) into hpS
    *(short8*)&hpS[srow][sc0] = *(const short8*)(hprevBf + (size_t)(m0 + srow) * 128 + sc0);

    // ---- pre-GEMM: ctx = elu(agg @ Wpre^T + b), wave w -> col-tile w, 2 row-tiles ----
    f32x4 accp[2] = {};
    #pragma unroll
    for (int ko = 0; ko < 4; ko++) {
        short8 bf = *(const short8*)(Bpre + ((size_t)(w * 4 + ko) * 64 + l) * 8);
        #pragma unroll
        for (int rt = 0; rt < 2; rt++) {
            short8 af = *(const short8*)(agg + (size_t)(m0 + rt * 16 + lr) * 128 + ko * 32 + lg * 8);
            accp[rt] = __builtin_amdgcn_mfma_f32_16x16x32_bf16(af, bf, accp[rt], 0, 0, 0);
        }
    }
    {
        const int col = w * 16 + lr;
        const float bb = bpre[col];
        #pragma unroll
        for (int rt = 0; rt < 2; rt++)
            #pragma unroll
            for (int r = 0; r < 4; r++)
                ctxS[rt * 16 + lg * 4 + r][col] = f2bf(elu_(accp[rt][r] + bb));
    }
    __syncthreads();

    // ---- GRU GEMMs: 12 accumulators per wave (2 row-tiles x 3 gates x {ih,hh}) ----
    f32x4 ai[2][3] = {}, ah[2][3] = {};
    #pragma unroll
    for (int ko = 0; ko < 4; ko++) {
        short8 afc[2], afh[2];
        #pragma unroll
        for (int rt = 0; rt < 2; rt++) {
            afc[rt] = *(const short8*)&ctxS[rt * 16 + lr][ko * 32 + lg * 8];
            afh[rt] = *(const short8*)&hpS[rt * 16 + lr][ko * 32 + lg * 8];
        }
        #pragma unroll
        for (int g = 0; g < 3; g++) {
            short8 bi = *(const short8*)(Bih + ((size_t)((w + 8 * g) * 4 + ko) * 64 + l) * 8);
            #pragma unroll
            for (int rt = 0; rt < 2; rt++)
                ai[rt][g] = __builtin_amdgcn_mfma_f32_16x16x32_bf16(afc[rt], bi, ai[rt][g], 0, 0, 0);
            short8 bh = *(const short8*)(Bhh + ((size_t)((w + 8 * g) * 4 + ko) * 64 + l) * 8);
            #pragma unroll
            for (int rt = 0; rt < 2; rt++)
                ah[rt][g] = __builtin_amdgcn_mfma_f32_16x16x32_bf16(afh[rt], bh, ah[rt][g], 0, 0, 0);
        }
    }
    __syncthreads();   // hpS A-reads done (gate phase reads hpS scalars, no overwrite)

    // ---- gates: channel c = w*16+lr, rows rt*16+lg*4+r (unique per thread) ----
    {
        const int c = w * 16 + lr;
        const float br = bih[c] + bhh[c];
        const float bz = bih[c + 128] + bhh[c + 128];
        const float bin_ = bih[c + 256];
        const float bhn = bhh[c + 256];
        #pragma unroll
        for (int rt = 0; rt < 2; rt++)
            #pragma unroll
            for (int r = 0; r < 4; r++) {
                const int lrow = rt * 16 + lg * 4 + r;
                float rg = sigmoidf_(ai[rt][0][r] + ah[rt][0][r] + br);
                float zg = sigmoidf_(ai[rt][1][r] + ah[rt][1][r] + bz);
                float ng = tanhf_(ai[rt][2][r] + bin_ + rg * (ah[rt][2][r] + bhn));
                float hp = bf2f(hpS[lrow][c]);
                hoS[lrow][c] = fmaf(zg, hp - ng, ng);
            }
    }
    __syncthreads();

    // ---- coalesced h writes ----
    {
        float v[8];
        #pragma unroll
        for (int k = 0; k < 8; k++) v[k] = hoS[srow][sc0 + k];
        f32x4* dst = (f32x4*)(houtF + (size_t)(m0 + srow) * 128 + sc0);
        dst[0] = *(f32x4*)v;
        dst[1] = *(f32x4*)(v + 4);
        if (FINAL == 0) {
            short8 p;
            #pragma unroll
            for (int k = 0; k < 8; k++) p[k] = (short)f2bf(v[k]);
            *(short8*)(houtBf + (size_t)(m0 + srow) * 128 + sc0) = p;
        }
    }

    if (FRONT) {
        int row = tid >> 4, q = tid & 15;
        float pa = 0.f, pb = 0.f;
        #pragma unroll
        for (int j = 0; j < 8; j++) {
            float x = hoS[row][q * 8 + j];
            pa = fmaf(x, w2att[q * 8 + j], pa);
            pb = fmaf(x, w2att[128 + q * 8 + j], pb);
        }
        #pragma unroll
        for (int m = 1; m <= 8; m <<= 1) {
            pa += __shfl_xor(pa, m, 16);
            pb += __shfl_xor(pb, m, 16);
        }
        if (q == 0) { aDOut[m0 + row] = pa; bSOut[m0 + row] = pb; }
    }

    if (FINAL) {
        // avg (coalesced) -> avgOut + ctxS(bf16)
        {
            const f32x4* p0 = (const f32x4*)(as0 + (size_t)(m0 + srow) * 128 + sc0);
            const f32x4* p1 = (const f32x4*)(as1 + (size_t)(m0 + srow) * 128 + sc0);
            f32x4* pav = (f32x4*)(avgOut + (size_t)(m0 + srow) * 128 + sc0);
            #pragma unroll
            for (int k = 0; k < 2; k++) {
                f32x4 x0 = p0[k], x1 = p1[k];
                f32x4 av;
                #pragma unroll
                for (int j = 0; j < 4; j++)
                    av[j] = (x0[j] + x1[j] + hoS[srow][sc0 + k * 4 + j]) * (1.f / 3.f);
                pav[k] = av;
                #pragma unroll
                for (int j = 0; j < 4; j++) ctxS[srow][sc0 + k * 4 + j] = f2bf(av[j]);
            }
        }
        __syncthreads();
        // lin GEMM: wave w -> col-tile w, 2 row-tiles
        f32x4 acc2[2] = {};
        #pragma unroll
        for (int ko = 0; ko < 4; ko++) {
            short8 bf = *(const short8*)(Blin + ((size_t)(w * 4 + ko) * 64 + l) * 8);
            #pragma unroll
            for (int rt = 0; rt < 2; rt++) {
                short8 af = *(const short8*)&ctxS[rt * 16 + lr][ko * 32 + lg * 8];
                acc2[rt] = __builtin_amdgcn_mfma_f32_16x16x32_bf16(af, bf, acc2[rt], 0, 0, 0);
            }
        }
        {
            const int col = w * 16 + lr;
            const float bb = linb[col];
            #pragma unroll
            for (int rt = 0; rt < 2; rt++)
                #pragma unroll
                for (int r = 0; r < 4; r++) {
                    float vv = acc2[rt][r] + bb;
                    hoS[rt * 16 + lg * 4 + r][col] =
                        0.5f * vv * (1.f + erff(vv * 0.70710678118654752f));
                }
        }
        __syncthreads();
        {
            float v[8];
            #pragma unroll
            for (int k = 0; k < 8; k++) v[k] = hoS[srow][sc0 + k];
            f32x4* dst = (f32x4*)(outF + (size_t)(m0 + srow) * 128 + sc0);
            dst[0] = *(f32x4*)v;
            dst[1] = *(f32x4*)(v + 4);
        }
    }
}

extern "C" void kernel_launch(void* const* d_in, const int* in_sizes, int n_in,
                              void* d_out, int out_size, void* d_ws, size_t ws_size,
                              hipStream_t stream) {
    const float* atom     = (const float*)d_in[0];
    const int*   esrc     = (const int*)d_in[1];
    const float* bond     = (const float*)d_in[3];
    const float* fc1_w    = (const float*)d_in[4];
    const float* fc1_b    = (const float*)d_in[5];
    const float* fc2_w    = (const float*)d_in[6];
    const float* fc2_b    = (const float*)d_in[7];
    const float* att_w    = (const float*)d_in[8];
    const float* att_b    = (const float*)d_in[9];
    const float* attend_w = (const float*)d_in[10];
    const float* attend_b = (const float*)d_in[11];
    const float* gih1     = (const float*)d_in[12];
    const float* ghh1     = (const float*)d_in[13];
    const float* bih1     = (const float*)d_in[14];
    const float* bhh1     = (const float*)d_in[15];
    const float* fc1v2_w  = (const float*)d_in[16];
    const float* fc1v2_b  = (const float*)d_in[17];
    const float* fc2v2_w  = (const float*)d_in[18];
    const float* fc2v2_b  = (const float*)d_in[19];
    const float* gih2     = (const float*)d_in[20];
    const float* ghh2     = (const float*)d_in[21];
    const float* bih2     = (const float*)d_in[22];
    const float* bhh2     = (const float*)d_in[23];
    const float* lin_w    = (const float*)d_in[24];
    const float* lin_b    = (const float*)d_in[25];

    char* wsb = (char*)d_ws;
    size_t off = 0;
    auto allocB = [&](size_t bytes) {
        size_t o = off; off = (off + bytes + 255) & ~(size_t)255; return o;
    };
    unsigned short* Bfc1   = (unsigned short*)(wsb + allocB(128 * 128 * 2));
    unsigned short* Batt   = (unsigned short*)(wsb + allocB(128 * 128 * 2));
    unsigned short* BW2a   = (unsigned short*)(wsb + allocB(128 * 128 * 2));
    unsigned short* BW2b   = (unsigned short*)(wsb + allocB(512 * 8 * 2));
    unsigned short* Bgih1  = (unsigned short*)(wsb + allocB(384 * 128 * 2));
    unsigned short* Bghh1  = (unsigned short*)(wsb + allocB(384 * 128 * 2));
    unsigned short* Bfc2v2 = (unsigned short*)(wsb + allocB(128 * 128 * 2));
    unsigned short* Bgih2  = (unsigned short*)(wsb + allocB(384 * 128 * 2));
    unsigned short* Bghh2  = (unsigned short*)(wsb + allocB(384 * 128 * 2));
    unsigned short* Blin   = (unsigned short*)(wsb + allocB(128 * 128 * 2));
    unsigned short* naBf   = (unsigned short*)(wsb + allocB((size_t)NN * 128 * 2));
    unsigned short* Ubf    = (unsigned short*)(wsb + allocB((size_t)NN * 128 * 2));
    unsigned short* aggBf  = (unsigned short*)(wsb + allocB((size_t)NN * 128 * 2));
    unsigned short* h1Bf   = (unsigned short*)(wsb + allocB((size_t)NN * 128 * 2));
    unsigned short* h2Bf   = (unsigned short*)(wsb + allocB((size_t)NN * 128 * 2));
    float* logits = (float*)(wsb + allocB((size_t)EE * 4));
    float* adst   = (float*)(wsb + allocB((size_t)NN * 4));
    float* aD     = (float*)(wsb + allocB((size_t)NN * 4));
    float* bS     = (float*)(wsb + allocB((size_t)NN * 4));
    (void)ws_size;

    float* out0 = (float*)d_out;
    float* as0  = out0 + (size_t)NN * 128;
    float* as1  = as0 + (size_t)NN * 128;
    float* as2  = as1 + (size_t)NN * 128;
    float* g0   = out0 + (size_t)4 * NN * 128;
    float* avg  = out0 + (size_t)5 * NN * 128;

    PackArgs pa;
    pa.d[0] = { fc1_w,    Bfc1,   128, 128, 0 };
    pa.d[1] = { attend_w, Batt,   128, 128, 0 };
    pa.d[2] = { fc2_w,    BW2a,   128, 144, 0 };
    pa.d[3] = { gih1,     Bgih1,  384, 128, 0 };
    pa.d[4] = { ghh1,     Bghh1,  384, 128, 0 };
    pa.d[5] = { fc2v2_w,  Bfc2v2, 128, 128, 0 };
    pa.d[6] = { gih2,     Bgih2,  384, 128, 0 };
    pa.d[7] = { ghh2,     Bghh2,  384, 128, 0 };
    pa.d[8] = { lin_w,    Blin,   128, 128, 0 };
    pa.d[9] = { fc2_w,    BW2b,   0,   0,   1 };
    k_pack<<<dim3(24, 10), 256, 0, stream>>>(pa);

    const int GB = NN / 16;     // 1250
    const int GB32 = NN / 32;   // 625

    // ---- V1 ----
    k_v1_front<<<GB, 256, 0, stream>>>(atom, Bfc1, BW2a, fc1_b, fc2_b, att_w,
                                       g0, naBf, Ubf, adst);
    k_logits_v1<<<NN / 4, 256, 0, stream>>>(Ubf, esrc, bond, BW2b, att_w, att_b,
                                            adst, logits);
    k_agg<0><<<GB, 256, 0, stream>>>(logits, nullptr, nullptr, nullptr, esrc, naBf, aggBf);
    k_gru<1, 0><<<GB32, 512, 0, stream>>>(
        aggBf, Batt, attend_b,
        Bgih1, Bghh1, bih1, bhh1, naBf, as0, h1Bf,
        fc1v2_w, aD, bS,
        nullptr, nullptr, nullptr, nullptr, nullptr, nullptr);

    // ---- V2 layer 2 ----
    k_agg<1><<<GB, 256, 0, stream>>>(nullptr, aD, bS, fc1v2_b, esrc, h1Bf, aggBf);
    k_gru<1, 0><<<GB32, 512, 0, stream>>>(
        aggBf, Bfc2v2, fc2v2_b,
        Bgih2, Bghh2, bih2, bhh2, h1Bf, as1, h2Bf,
        fc1v2_w, aD, bS,
        nullptr, nullptr, nullptr, nullptr, nullptr, nullptr);

    // ---- V2 layer 3 + final ----
    k_agg<1><<<GB, 256, 0, stream>>>(nullptr, aD, bS, fc1v2_b, esrc, h2Bf, aggBf);
    k_gru<0, 1><<<GB32, 512, 0, stream>>>(
        aggBf, Bfc2v2, fc2v2_b,
        Bgih2, Bghh2, bih2, bhh2, h2Bf, as2, nullptr,
        nullptr, nullptr, nullptr,
        as0, as1, Blin, lin_b, avg, out0);
}

// Round 10
// 126.723 us; speedup vs baseline: 1.3949x; 1.1263x over previous
//
#include <hip/hip_runtime.h>
#include <math.h>

#define NN 20000
#define EE 320000

using short8 = __attribute__((ext_vector_type(8))) short;
using f32x4  = __attribute__((ext_vector_type(4))) float;
using u16x4  = __attribute__((ext_vector_type(4))) unsigned short;

__device__ __forceinline__ unsigned short f2bf(float x) {
    union { float f; unsigned u; } v; v.f = x;
    unsigned r = (v.u + 0x7fffu + ((v.u >> 16) & 1u)) >> 16;
    return (unsigned short)r;
}
__device__ __forceinline__ float bf2f(unsigned short b) {
    union { unsigned u; float f; } v; v.u = ((unsigned)b) << 16;
    return v.f;
}
__device__ __forceinline__ float sigmoidf_(float x) { return 1.f / (1.f + __expf(-x)); }
__device__ __forceinline__ float tanhf_(float x) {
    float e = __expf(-2.f * x);
    return (1.f - e) / (1.f + e);
}
__device__ __forceinline__ float lrelu_(float x) { return x > 0.f ? x : 0.2f * x; }
__device__ __forceinline__ float elu_(float x) { return x > 0.f ? x : __expf(x) - 1.f; }

// ---------------- weight pack into MFMA B-fragment layout ----------------
struct PackDesc { const float* w; unsigned short* out; int O; int ldw; int mode; };
struct PackArgs { PackDesc d[10]; };

__global__ void k_pack(PackArgs args) {
    PackDesc d = args.d[blockIdx.y];
    int idx = blockIdx.x * 256 + threadIdx.x;
    if (d.mode == 1) {   // W2b: bond part of fc2_w, K=32 zero-padded
        if (idx >= 512) return;
        int t = idx >> 6, l = idx & 63;
        int lr = l & 15, lg = l >> 4;
        int ch = lr * 8 + t;
        short8 o;
        #pragma unroll
        for (int j = 0; j < 8; j++) {
            int k = lg * 8 + j;
            o[j] = (k < 16) ? (short)f2bf(d.w[(size_t)ch * 144 + 128 + k]) : (short)0;
        }
        *(short8*)(d.out + (size_t)idx * 8) = o;
        return;
    }
    int total = (d.O / 16) * 4 * 64;
    if (idx >= total) return;
    int l = idx & 63, rest = idx >> 6;
    int ko = rest & 3, no = rest >> 2;
    int row = no * 16 + (l & 15);
    int col0 = ko * 32 + ((l >> 4) * 8);
    const float* src = d.w + (size_t)row * d.ldw + col0;
    unsigned short o[8];
    #pragma unroll
    for (int j = 0; j < 8; j++) o[j] = f2bf(src[j]);
    #pragma unroll
    for (int j = 0; j < 8; j++) d.out[(size_t)idx * 8 + j] = o[j];
}

// ---------------- V1 front ----------------
__global__ __launch_bounds__(256) void k_v1_front(
    const float* __restrict__ atom,
    const unsigned short* __restrict__ Bfc1, const unsigned short* __restrict__ BW2a,
    const float* __restrict__ fc1_b, const float* __restrict__ fc2_b,
    const float* __restrict__ attw,
    float* __restrict__ g0, unsigned short* __restrict__ naBf,
    unsigned short* __restrict__ Ubf, float* __restrict__ adst)
{
    __shared__ float Xs[16][132];
    __shared__ unsigned short Ys2[16 * 128];
    const int tid = threadIdx.x, l = tid & 63, w = tid >> 6;
    const int lr = l & 15, lg = l >> 4;
    const int m0 = blockIdx.x * 16;

    f32x4 acc1[2] = {}, accU[2] = {};
    #pragma unroll
    for (int ko = 0; ko < 4; ko++) {
        const f32x4* ap = (const f32x4*)(atom + (size_t)(m0 + lr) * 128 + ko * 32 + lg * 8);
        f32x4 a0 = ap[0], a1 = ap[1];
        short8 af;
        #pragma unroll
        for (int j = 0; j < 4; j++) { af[j] = (short)f2bf(a0[j]); af[4 + j] = (short)f2bf(a1[j]); }
        #pragma unroll
        for (int i = 0; i < 2; i++) {
            int t = w * 2 + i;
            short8 b1 = *(const short8*)(Bfc1 + ((size_t)(t * 4 + ko) * 64 + l) * 8);
            acc1[i] = __builtin_amdgcn_mfma_f32_16x16x32_bf16(af, b1, acc1[i], 0, 0, 0);
            short8 bu = *(const short8*)(BW2a + ((size_t)(t * 4 + ko) * 64 + l) * 8);
            accU[i] = __builtin_amdgcn_mfma_f32_16x16x32_bf16(af, bu, accU[i], 0, 0, 0);
        }
    }
    #pragma unroll
    for (int i = 0; i < 2; i++) {
        int col = (w * 2 + i) * 16 + lr;
        float b1v = fc1_b[col], bUv = fc2_b[col];
        #pragma unroll
        for (int r = 0; r < 4; r++) {
            int row = lg * 4 + r;
            float v = lrelu_(acc1[i][r] + b1v);
            Xs[row][col] = v;
            Ys2[row * 128 + col] = f2bf(accU[i][r] + bUv);
        }
    }
    __syncthreads();
    *(short8*)(Ubf + (size_t)m0 * 128 + tid * 8) = *(const short8*)(Ys2 + tid * 8);
    {
        int row = tid >> 4, q = tid & 15;
        short8 tmp;
        float p = 0.f;
        float vv[8];
        #pragma unroll
        for (int j = 0; j < 8; j++) {
            float x = Xs[row][q * 8 + j];
            vv[j] = x;
            tmp[j] = (short)f2bf(x);
            p = fmaf(x, attw[q * 8 + j], p);
        }
        *(f32x4*)(g0 + (size_t)(m0 + row) * 128 + q * 8) = *(f32x4*)vv;
        *(f32x4*)(g0 + (size_t)(m0 + row) * 128 + q * 8 + 4) = *(f32x4*)(vv + 4);
        *(short8*)(naBf + (size_t)(m0 + row) * 128 + q * 8) = tmp;
        #pragma unroll
        for (int m = 1; m <= 8; m <<= 1) p += __shfl_xor(p, m, 16);
        if (q == 0) adst[m0 + row] = p;
    }
}

// ---------------- V1 edge logits ----------------
__global__ __launch_bounds__(256) void k_logits_v1(
    const unsigned short* __restrict__ U, const int* __restrict__ esrc,
    const float* __restrict__ bond, const unsigned short* __restrict__ BW2b,
    const float* __restrict__ attw, const float* __restrict__ attb1,
    const float* __restrict__ adst, float* __restrict__ logits)
{
    const int tid = threadIdx.x, l = tid & 63, w = tid >> 6;
    const int lr = l & 15, lg = l >> 4;
    const int n = blockIdx.x * 4 + w;
    const int e0 = n * 16;

    short8 af = {};
    if (lg < 2) {
        const f32x4* bp = (const f32x4*)(bond + (size_t)(e0 + lr) * 16 + lg * 8);
        f32x4 b0 = bp[0], b1 = bp[1];
        #pragma unroll
        for (int j = 0; j < 4; j++) { af[j] = (short)f2bf(b0[j]); af[4 + j] = (short)f2bf(b1[j]); }
    }
    f32x4 c[8];
    #pragma unroll
    for (int t = 0; t < 8; t++) {
        short8 bf = *(const short8*)(BW2b + (size_t)(t * 64 + l) * 8);
        f32x4 z = {};
        c[t] = __builtin_amdgcn_mfma_f32_16x16x32_bf16(af, bf, z, 0, 0, 0);
    }
    float aw[8];
    #pragma unroll
    for (int t = 0; t < 8; t++) aw[t] = attw[128 + lr * 8 + t];

    float s[4];
    #pragma unroll
    for (int r = 0; r < 4; r++) {
        int e = e0 + lg * 4 + r;
        int src = esrc[e];
        short8 u = *(const short8*)(U + (size_t)src * 128 + lr * 8);
        float a0 = 0.f;
        #pragma unroll
        for (int t = 0; t < 8; t++)
            a0 = fmaf(aw[t], lrelu_(c[t][r] + bf2f((unsigned short)u[t])), a0);
        s[r] = a0;
    }
    #pragma unroll
    for (int mk = 1; mk <= 8; mk <<= 1)
        #pragma unroll
        for (int r = 0; r < 4; r++) s[r] += __shfl_xor(s[r], mk, 16);
    if (lr == 0) {
        float anode = adst[n], ab = attb1[0];
        f32x4 o;
        #pragma unroll
        for (int r = 0; r < 4; r++) o[r] = lrelu_(anode + ab + s[r]);
        *(f32x4*)(logits + e0 + lg * 4) = o;
    }
}

// ---------------- GRU: 32-row blocks, 512 threads (8 waves), fused aggregation ----
// Prologue: per-node (16-lane group) softmax + gather V rows -> aggS (raw sum, bf16).
// AGGMODE 0: logits from buffer (V1). AGGMODE 1: inline logits aD[dst]+bS[src]+b (V2).
// Then: ctx = elu(aggS @ Wpre^T + b); GRU GEMMs (bf16 h-prev from LDS); gates;
// FRONT: next-layer aD/bS dots; FINAL: avg + lin + gelu.
template<int AGGMODE, int FRONT, int FINAL>
__global__ __launch_bounds__(512, 4) void k_gru(
    const float* __restrict__ logits, const float* __restrict__ aD,
    const float* __restrict__ bS, const float* __restrict__ b1,
    const int* __restrict__ esrc, const unsigned short* __restrict__ V,
    const unsigned short* __restrict__ Bpre, const float* __restrict__ bpre,
    const unsigned short* __restrict__ Bih, const unsigned short* __restrict__ Bhh,
    const float* __restrict__ bih, const float* __restrict__ bhh,
    const unsigned short* __restrict__ hprevBf, float* __restrict__ houtF,
    unsigned short* __restrict__ houtBf,
    const float* __restrict__ w2att, float* __restrict__ aDOut, float* __restrict__ bSOut,
    const float* __restrict__ as0, const float* __restrict__ as1,
    const unsigned short* __restrict__ Blin, const float* __restrict__ linb,
    float* __restrict__ avgOut, float* __restrict__ outF)
{
    __shared__ unsigned short aggS[32][136];
    __shared__ unsigned short ctxS[32][136];
    __shared__ unsigned short hpS[32][136];
    __shared__ float hoS[32][132];
    const int tid = threadIdx.x, l = tid & 63, w = tid >> 6;   // w in 0..7
    const int lr = l & 15, lg = l >> 4;
    const int m0 = blockIdx.x * 32;
    const int srow = tid >> 4, sc0 = (tid & 15) * 8;           // 16B/thread staging map

    // stage bf16 hprev (coalesced) into hpS
    *(short8*)&hpS[srow][sc0] = *(const short8*)(hprevBf + (size_t)(m0 + srow) * 128 + sc0);

    // ---- fused aggregation: node srow, edge-lane q ----
    {
        const int q = tid & 15;
        const int gnode = m0 + srow;
        const int e = gnode * 16 + q;
        const int src = esrc[e];
        float lgt;
        if (AGGMODE == 0) lgt = logits[e];
        else              lgt = lrelu_(aD[gnode] + bS[src] + b1[0]);
        float mx = lgt;
        #pragma unroll
        for (int mk = 1; mk <= 8; mk <<= 1) mx = fmaxf(mx, __shfl_xor(mx, mk, 16));
        float ex = __expf(lgt - mx);
        float den = ex;
        #pragma unroll
        for (int mk = 1; mk <= 8; mk <<= 1) den += __shfl_xor(den, mk, 16);
        float wq = ex / den;
        float s[8] = {};
        #pragma unroll
        for (int i = 0; i < 16; i++) {
            float wi = __shfl(wq, i, 16);
            int si = __shfl(src, i, 16);
            const unsigned short* vp = V + (size_t)si * 128 + q * 4;
            u16x4 v0 = *(const u16x4*)vp;
            #pragma unroll
            for (int j = 0; j < 4; j++) s[j] = fmaf(wi, bf2f(v0[j]), s[j]);
            u16x4 v1 = *(const u16x4*)(vp + 64);
            #pragma unroll
            for (int j = 0; j < 4; j++) s[4 + j] = fmaf(wi, bf2f(v1[j]), s[4 + j]);
        }
        u16x4 o0, o1;
        #pragma unroll
        for (int j = 0; j < 4; j++) { o0[j] = f2bf(s[j]); o1[j] = f2bf(s[4 + j]); }
        *(u16x4*)&aggS[srow][q * 4] = o0;
        *(u16x4*)&aggS[srow][64 + q * 4] = o1;
    }
    __syncthreads();

    // ---- pre-GEMM: ctx = elu(aggS @ Wpre^T + b), wave w -> col-tile w, 2 row-tiles ----
    f32x4 accp[2] = {};
    #pragma unroll
    for (int ko = 0; ko < 4; ko++) {
        short8 bf = *(const short8*)(Bpre + ((size_t)(w * 4 + ko) * 64 + l) * 8);
        #pragma unroll
        for (int rt = 0; rt < 2; rt++) {
            short8 af = *(const short8*)&aggS[rt * 16 + lr][ko * 32 + lg * 8];
            accp[rt] = __builtin_amdgcn_mfma_f32_16x16x32_bf16(af, bf, accp[rt], 0, 0, 0);
        }
    }
    {
        const int col = w * 16 + lr;
        const float bb = bpre[col];
        #pragma unroll
        for (int rt = 0; rt < 2; rt++)
            #pragma unroll
            for (int r = 0; r < 4; r++)
                ctxS[rt * 16 + lg * 4 + r][col] = f2bf(elu_(accp[rt][r] + bb));
    }
    __syncthreads();

    // ---- GRU GEMMs: 12 accumulators per wave (2 row-tiles x 3 gates x {ih,hh}) ----
    f32x4 ai[2][3] = {}, ah[2][3] = {};
    #pragma unroll
    for (int ko = 0; ko < 4; ko++) {
        short8 afc[2], afh[2];
        #pragma unroll
        for (int rt = 0; rt < 2; rt++) {
            afc[rt] = *(const short8*)&ctxS[rt * 16 + lr][ko * 32 + lg * 8];
            afh[rt] = *(const short8*)&hpS[rt * 16 + lr][ko * 32 + lg * 8];
        }
        #pragma unroll
        for (int g = 0; g < 3; g++) {
            short8 bi = *(const short8*)(Bih + ((size_t)((w + 8 * g) * 4 + ko) * 64 + l) * 8);
            #pragma unroll
            for (int rt = 0; rt < 2; rt++)
                ai[rt][g] = __builtin_amdgcn_mfma_f32_16x16x32_bf16(afc[rt], bi, ai[rt][g], 0, 0, 0);
            short8 bh = *(const short8*)(Bhh + ((size_t)((w + 8 * g) * 4 + ko) * 64 + l) * 8);
            #pragma unroll
            for (int rt = 0; rt < 2; rt++)
                ah[rt][g] = __builtin_amdgcn_mfma_f32_16x16x32_bf16(afh[rt], bh, ah[rt][g], 0, 0, 0);
        }
    }
    __syncthreads();   // hpS A-reads done (gate phase reads hpS scalars, no overwrite)

    // ---- gates: channel c = w*16+lr, rows rt*16+lg*4+r (unique per thread) ----
    {
        const int c = w * 16 + lr;
        const float br = bih[c] + bhh[c];
        const float bz = bih[c + 128] + bhh[c + 128];
        const float bin_ = bih[c + 256];
        const float bhn = bhh[c + 256];
        #pragma unroll
        for (int rt = 0; rt < 2; rt++)
            #pragma unroll
            for (int r = 0; r < 4; r++) {
                const int lrow = rt * 16 + lg * 4 + r;
                float rg = sigmoidf_(ai[rt][0][r] + ah[rt][0][r] + br);
                float zg = sigmoidf_(ai[rt][1][r] + ah[rt][1][r] + bz);
                float ng = tanhf_(ai[rt][2][r] + bin_ + rg * (ah[rt][2][r] + bhn));
                float hp = bf2f(hpS[lrow][c]);
                hoS[lrow][c] = fmaf(zg, hp - ng, ng);
            }
    }
    __syncthreads();

    // ---- coalesced h writes ----
    {
        float v[8];
        #pragma unroll
        for (int k = 0; k < 8; k++) v[k] = hoS[srow][sc0 + k];
        f32x4* dst = (f32x4*)(houtF + (size_t)(m0 + srow) * 128 + sc0);
        dst[0] = *(f32x4*)v;
        dst[1] = *(f32x4*)(v + 4);
        if (FINAL == 0) {
            short8 p;
            #pragma unroll
            for (int k = 0; k < 8; k++) p[k] = (short)f2bf(v[k]);
            *(short8*)(houtBf + (size_t)(m0 + srow) * 128 + sc0) = p;
        }
    }

    if (FRONT) {
        int row = tid >> 4, q = tid & 15;
        float pa = 0.f, pb = 0.f;
        #pragma unroll
        for (int j = 0; j < 8; j++) {
            float x = hoS[row][q * 8 + j];
            pa = fmaf(x, w2att[q * 8 + j], pa);
            pb = fmaf(x, w2att[128 + q * 8 + j], pb);
        }
        #pragma unroll
        for (int m = 1; m <= 8; m <<= 1) {
            pa += __shfl_xor(pa, m, 16);
            pb += __shfl_xor(pb, m, 16);
        }
        if (q == 0) { aDOut[m0 + row] = pa; bSOut[m0 + row] = pb; }
    }

    if (FINAL) {
        // avg (coalesced) -> avgOut + ctxS(bf16)
        {
            const f32x4* p0 = (const f32x4*)(as0 + (size_t)(m0 + srow) * 128 + sc0);
            const f32x4* p1 = (const f32x4*)(as1 + (size_t)(m0 + srow) * 128 + sc0);
            f32x4* pav = (f32x4*)(avgOut + (size_t)(m0 + srow) * 128 + sc0);
            #pragma unroll
            for (int k = 0; k < 2; k++) {
                f32x4 x0 = p0[k], x1 = p1[k];
                f32x4 av;
                #pragma unroll
                for (int j = 0; j < 4; j++)
                    av[j] = (x0[j] + x1[j] + hoS[srow][sc0 + k * 4 + j]) * (1.f / 3.f);
                pav[k] = av;
                #pragma unroll
                for (int j = 0; j < 4; j++) ctxS[srow][sc0 + k * 4 + j] = f2bf(av[j]);
            }
        }
        __syncthreads();
        // lin GEMM: wave w -> col-tile w, 2 row-tiles
        f32x4 acc2[2] = {};
        #pragma unroll
        for (int ko = 0; ko < 4; ko++) {
            short8 bf = *(const short8*)(Blin + ((size_t)(w * 4 + ko) * 64 + l) * 8);
            #pragma unroll
            for (int rt = 0; rt < 2; rt++) {
                short8 af = *(const short8*)&ctxS[rt * 16 + lr][ko * 32 + lg * 8];
                acc2[rt] = __builtin_amdgcn_mfma_f32_16x16x32_bf16(af, bf, acc2[rt], 0, 0, 0);
            }
        }
        {
            const int col = w * 16 + lr;
            const float bb = linb[col];
            #pragma unroll
            for (int rt = 0; rt < 2; rt++)
                #pragma unroll
                for (int r = 0; r < 4; r++) {
                    float vv = acc2[rt][r] + bb;
                    hoS[rt * 16 + lg * 4 + r][col] =
                        0.5f * vv * (1.f + erff(vv * 0.70710678118654752f));
                }
        }
        __syncthreads();
        {
            float v[8];
            #pragma unroll
            for (int k = 0; k < 8; k++) v[k] = hoS[srow][sc0 + k];
            f32x4* dst = (f32x4*)(outF + (size_t)(m0 + srow) * 128 + sc0);
            dst[0] = *(f32x4*)v;
            dst[1] = *(f32x4*)(v + 4);
        }
    }
}

extern "C" void kernel_launch(void* const* d_in, const int* in_sizes, int n_in,
                              void* d_out, int out_size, void* d_ws, size_t ws_size,
                              hipStream_t stream) {
    const float* atom     = (const float*)d_in[0];
    const int*   esrc     = (const int*)d_in[1];
    const float* bond     = (const float*)d_in[3];
    const float* fc1_w    = (const float*)d_in[4];
    const float* fc1_b    = (const float*)d_in[5];
    const float* fc2_w    = (const float*)d_in[6];
    const float* fc2_b    = (const float*)d_in[7];
    const float* att_w    = (const float*)d_in[8];
    const float* att_b    = (const float*)d_in[9];
    const float* attend_w = (const float*)d_in[10];
    const float* attend_b = (const float*)d_in[11];
    const float* gih1     = (const float*)d_in[12];
    const float* ghh1     = (const float*)d_in[13];
    const float* bih1     = (const float*)d_in[14];
    const float* bhh1     = (const float*)d_in[15];
    const float* fc1v2_w  = (const float*)d_in[16];
    const float* fc1v2_b  = (const float*)d_in[17];
    const float* fc2v2_w  = (const float*)d_in[18];
    const float* fc2v2_b  = (const float*)d_in[19];
    const float* gih2     = (const float*)d_in[20];
    const float* ghh2     = (const float*)d_in[21];
    const float* bih2     = (const float*)d_in[22];
    const float* bhh2     = (const float*)d_in[23];
    const float* lin_w    = (const float*)d_in[24];
    const float* lin_b    = (const float*)d_in[25];

    char* wsb = (char*)d_ws;
    size_t off = 0;
    auto allocB = [&](size_t bytes) {
        size_t o = off; off = (off + bytes + 255) & ~(size_t)255; return o;
    };
    unsigned short* Bfc1   = (unsigned short*)(wsb + allocB(128 * 128 * 2));
    unsigned short* Batt   = (unsigned short*)(wsb + allocB(128 * 128 * 2));
    unsigned short* BW2a   = (unsigned short*)(wsb + allocB(128 * 128 * 2));
    unsigned short* BW2b   = (unsigned short*)(wsb + allocB(512 * 8 * 2));
    unsigned short* Bgih1  = (unsigned short*)(wsb + allocB(384 * 128 * 2));
    unsigned short* Bghh1  = (unsigned short*)(wsb + allocB(384 * 128 * 2));
    unsigned short* Bfc2v2 = (unsigned short*)(wsb + allocB(128 * 128 * 2));
    unsigned short* Bgih2  = (unsigned short*)(wsb + allocB(384 * 128 * 2));
    unsigned short* Bghh2  = (unsigned short*)(wsb + allocB(384 * 128 * 2));
    unsigned short* Blin   = (unsigned short*)(wsb + allocB(128 * 128 * 2));
    unsigned short* naBf   = (unsigned short*)(wsb + allocB((size_t)NN * 128 * 2));
    unsigned short* Ubf    = (unsigned short*)(wsb + allocB((size_t)NN * 128 * 2));
    unsigned short* h1Bf   = (unsigned short*)(wsb + allocB((size_t)NN * 128 * 2));
    unsigned short* h2Bf   = (unsigned short*)(wsb + allocB((size_t)NN * 128 * 2));
    float* logits = (float*)(wsb + allocB((size_t)EE * 4));
    float* adst   = (float*)(wsb + allocB((size_t)NN * 4));
    float* aD     = (float*)(wsb + allocB((size_t)NN * 4));
    float* bS     = (float*)(wsb + allocB((size_t)NN * 4));
    (void)ws_size;

    float* out0 = (float*)d_out;
    float* as0  = out0 + (size_t)NN * 128;
    float* as1  = as0 + (size_t)NN * 128;
    float* as2  = as1 + (size_t)NN * 128;
    float* g0   = out0 + (size_t)4 * NN * 128;
    float* avg  = out0 + (size_t)5 * NN * 128;

    PackArgs pa;
    pa.d[0] = { fc1_w,    Bfc1,   128, 128, 0 };
    pa.d[1] = { attend_w, Batt,   128, 128, 0 };
    pa.d[2] = { fc2_w,    BW2a,   128, 144, 0 };
    pa.d[3] = { gih1,     Bgih1,  384, 128, 0 };
    pa.d[4] = { ghh1,     Bghh1,  384, 128, 0 };
    pa.d[5] = { fc2v2_w,  Bfc2v2, 128, 128, 0 };
    pa.d[6] = { gih2,     Bgih2,  384, 128, 0 };
    pa.d[7] = { ghh2,     Bghh2,  384, 128, 0 };
    pa.d[8] = { lin_w,    Blin,   128, 128, 0 };
    pa.d[9] = { fc2_w,    BW2b,   0,   0,   1 };
    k_pack<<<dim3(24, 10), 256, 0, stream>>>(pa);

    const int GB = NN / 16;     // 1250
    const int GB32 = NN / 32;   // 625

    // ---- V1 ----
    k_v1_front<<<GB, 256, 0, stream>>>(atom, Bfc1, BW2a, fc1_b, fc2_b, att_w,
                                       g0, naBf, Ubf, adst);
    k_logits_v1<<<NN / 4, 256, 0, stream>>>(Ubf, esrc, bond, BW2b, att_w, att_b,
                                            adst, logits);
    k_gru<0, 1, 0><<<GB32, 512, 0, stream>>>(
        logits, nullptr, nullptr, nullptr, esrc, naBf,
        Batt, attend_b,
        Bgih1, Bghh1, bih1, bhh1, naBf, as0, h1Bf,
        fc1v2_w, aD, bS,
        nullptr, nullptr, nullptr, nullptr, nullptr, nullptr);

    // ---- V2 layer 2 ----
    k_gru<1, 1, 0><<<GB32, 512, 0, stream>>>(
        nullptr, aD, bS, fc1v2_b, esrc, h1Bf,
        Bfc2v2, fc2v2_b,
        Bgih2, Bghh2, bih2, bhh2, h1Bf, as1, h2Bf,
        fc1v2_w, aD, bS,
        nullptr, nullptr, nullptr, nullptr, nullptr, nullptr);

    // ---- V2 layer 3 + final ----
    k_gru<1, 0, 1><<<GB32, 512, 0, stream>>>(
        nullptr, aD, bS, fc1v2_b, esrc, h2Bf,
        Bfc2v2, fc2v2_b,
        Bgih2, Bghh2, bih2, bhh2, h2Bf, as2, nullptr,
        nullptr, nullptr, nullptr,
        as0, as1, Blin, lin_b, avg, out0);
}

// Round 11
// 123.271 us; speedup vs baseline: 1.4339x; 1.0280x over previous
//
#include <hip/hip_runtime.h>
#include <math.h>

#define NN 20000
#define EE 320000

using short8 = __attribute__((ext_vector_type(8))) short;
using f32x4  = __attribute__((ext_vector_type(4))) float;
using u16x4  = __attribute__((ext_vector_type(4))) unsigned short;

__device__ __forceinline__ unsigned short f2bf(float x) {
    union { float f; unsigned u; } v; v.f = x;
    unsigned r = (v.u + 0x7fffu + ((v.u >> 16) & 1u)) >> 16;
    return (unsigned short)r;
}
__device__ __forceinline__ float bf2f(unsigned short b) {
    union { unsigned u; float f; } v; v.u = ((unsigned)b) << 16;
    return v.f;
}
__device__ __forceinline__ float sigmoidf_(float x) { return 1.f / (1.f + __expf(-x)); }
__device__ __forceinline__ float tanhf_(float x) {
    float e = __expf(-2.f * x);
    return (1.f - e) / (1.f + e);
}
__device__ __forceinline__ float lrelu_(float x) { return x > 0.f ? x : 0.2f * x; }
__device__ __forceinline__ float elu_(float x) { return x > 0.f ? x : __expf(x) - 1.f; }

// ---------------- weight pack into MFMA B-fragment layout ----------------
struct PackDesc { const float* w; unsigned short* out; int O; int ldw; int mode; };
struct PackArgs { PackDesc d[10]; };

__global__ void k_pack(PackArgs args) {
    PackDesc d = args.d[blockIdx.y];
    int idx = blockIdx.x * 256 + threadIdx.x;
    if (d.mode == 1) {   // W2b: bond part of fc2_w, K=32 zero-padded
        if (idx >= 512) return;
        int t = idx >> 6, l = idx & 63;
        int lr = l & 15, lg = l >> 4;
        int ch = lr * 8 + t;
        short8 o;
        #pragma unroll
        for (int j = 0; j < 8; j++) {
            int k = lg * 8 + j;
            o[j] = (k < 16) ? (short)f2bf(d.w[(size_t)ch * 144 + 128 + k]) : (short)0;
        }
        *(short8*)(d.out + (size_t)idx * 8) = o;
        return;
    }
    int total = (d.O / 16) * 4 * 64;
    if (idx >= total) return;
    int l = idx & 63, rest = idx >> 6;
    int ko = rest & 3, no = rest >> 2;
    int row = no * 16 + (l & 15);
    int col0 = ko * 32 + ((l >> 4) * 8);
    const float* src = d.w + (size_t)row * d.ldw + col0;
    unsigned short o[8];
    #pragma unroll
    for (int j = 0; j < 8; j++) o[j] = f2bf(src[j]);
    #pragma unroll
    for (int j = 0; j < 8; j++) d.out[(size_t)idx * 8 + j] = o[j];
}

// ---------------- V1 front ----------------
__global__ __launch_bounds__(256) void k_v1_front(
    const float* __restrict__ atom,
    const unsigned short* __restrict__ Bfc1, const unsigned short* __restrict__ BW2a,
    const float* __restrict__ fc1_b, const float* __restrict__ fc2_b,
    const float* __restrict__ attw,
    float* __restrict__ g0, unsigned short* __restrict__ naBf,
    unsigned short* __restrict__ Ubf, float* __restrict__ adst)
{
    __shared__ float Xs[16][132];
    __shared__ unsigned short Ys2[16 * 128];
    const int tid = threadIdx.x, l = tid & 63, w = tid >> 6;
    const int lr = l & 15, lg = l >> 4;
    const int m0 = blockIdx.x * 16;

    f32x4 acc1[2] = {}, accU[2] = {};
    #pragma unroll
    for (int ko = 0; ko < 4; ko++) {
        const f32x4* ap = (const f32x4*)(atom + (size_t)(m0 + lr) * 128 + ko * 32 + lg * 8);
        f32x4 a0 = ap[0], a1 = ap[1];
        short8 af;
        #pragma unroll
        for (int j = 0; j < 4; j++) { af[j] = (short)f2bf(a0[j]); af[4 + j] = (short)f2bf(a1[j]); }
        #pragma unroll
        for (int i = 0; i < 2; i++) {
            int t = w * 2 + i;
            short8 b1 = *(const short8*)(Bfc1 + ((size_t)(t * 4 + ko) * 64 + l) * 8);
            acc1[i] = __builtin_amdgcn_mfma_f32_16x16x32_bf16(af, b1, acc1[i], 0, 0, 0);
            short8 bu = *(const short8*)(BW2a + ((size_t)(t * 4 + ko) * 64 + l) * 8);
            accU[i] = __builtin_amdgcn_mfma_f32_16x16x32_bf16(af, bu, accU[i], 0, 0, 0);
        }
    }
    #pragma unroll
    for (int i = 0; i < 2; i++) {
        int col = (w * 2 + i) * 16 + lr;
        float b1v = fc1_b[col], bUv = fc2_b[col];
        #pragma unroll
        for (int r = 0; r < 4; r++) {
            int row = lg * 4 + r;
            float v = lrelu_(acc1[i][r] + b1v);
            Xs[row][col] = v;
            Ys2[row * 128 + col] = f2bf(accU[i][r] + bUv);
        }
    }
    __syncthreads();
    *(short8*)(Ubf + (size_t)m0 * 128 + tid * 8) = *(const short8*)(Ys2 + tid * 8);
    {
        int row = tid >> 4, q = tid & 15;
        short8 tmp;
        float p = 0.f;
        float vv[8];
        #pragma unroll
        for (int j = 0; j < 8; j++) {
            float x = Xs[row][q * 8 + j];
            vv[j] = x;
            tmp[j] = (short)f2bf(x);
            p = fmaf(x, attw[q * 8 + j], p);
        }
        *(f32x4*)(g0 + (size_t)(m0 + row) * 128 + q * 8) = *(f32x4*)vv;
        *(f32x4*)(g0 + (size_t)(m0 + row) * 128 + q * 8 + 4) = *(f32x4*)(vv + 4);
        *(short8*)(naBf + (size_t)(m0 + row) * 128 + q * 8) = tmp;
        #pragma unroll
        for (int m = 1; m <= 8; m <<= 1) p += __shfl_xor(p, m, 16);
        if (q == 0) adst[m0 + row] = p;
    }
}

// ---------------- GRU: 32-row blocks, 512 threads (8 waves) ----------------
// AGGMODE 0 (V1): fused edge logits (bond MFMA + U decomposition) -> lgS, then
//   softmax + gather -> aggS. AGGMODE 1 (V2): inline logits aD[dst]+bS[src]+b.
// Phase1: pre-GEMM (aggS) + hh GEMMs (hpS) together. Phase2: ih GEMMs + gates.
// FRONT: next-layer aD/bS dots. FINAL: avg + lin + gelu.
template<int AGGMODE, int FRONT, int FINAL>
__global__ __launch_bounds__(512, 4) void k_gru(
    const float* __restrict__ aD, const float* __restrict__ bS, const float* __restrict__ b1,
    const float* __restrict__ bond, const unsigned short* __restrict__ BW2b,
    const float* __restrict__ attw, const float* __restrict__ attb1,
    const float* __restrict__ adst, const unsigned short* __restrict__ U,
    const int* __restrict__ esrc, const unsigned short* __restrict__ V,
    const unsigned short* __restrict__ Bpre, const float* __restrict__ bpre,
    const unsigned short* __restrict__ Bih, const unsigned short* __restrict__ Bhh,
    const float* __restrict__ bih, const float* __restrict__ bhh,
    const unsigned short* __restrict__ hprevBf, float* __restrict__ houtF,
    unsigned short* __restrict__ houtBf,
    const float* __restrict__ w2att, float* __restrict__ aDOut, float* __restrict__ bSOut,
    const float* __restrict__ as0, const float* __restrict__ as1,
    const unsigned short* __restrict__ Blin, const float* __restrict__ linb,
    float* __restrict__ avgOut, float* __restrict__ outF)
{
    __shared__ unsigned short aggS[32][136];
    __shared__ unsigned short ctxS[32][136];
    __shared__ unsigned short hpS[32][136];
    __shared__ float hoS[32][132];
    __shared__ float lgS[32][16];
    const int tid = threadIdx.x, l = tid & 63, w = tid >> 6;   // w in 0..7
    const int lr = l & 15, lg = l >> 4;
    const int m0 = blockIdx.x * 32;
    const int srow = tid >> 4, sc0 = (tid & 15) * 8;           // 16B/thread staging map

    // stage bf16 hprev (coalesced) into hpS
    *(short8*)&hpS[srow][sc0] = *(const short8*)(hprevBf + (size_t)(m0 + srow) * 128 + sc0);

    if (AGGMODE == 0) {
        // ---- fused V1 edge logits: wave w handles nodes m0 + w*4 + 0..3 ----
        float aw[8];
        #pragma unroll
        for (int t = 0; t < 8; t++) aw[t] = attw[128 + lr * 8 + t];
        const float ab = attb1[0];
        #pragma unroll
        for (int nn = 0; nn < 4; nn++) {
            const int n = m0 + w * 4 + nn;
            const int e0 = n * 16;
            short8 af = {};
            if (lg < 2) {
                const f32x4* bp = (const f32x4*)(bond + (size_t)(e0 + lr) * 16 + lg * 8);
                f32x4 b0 = bp[0], b1v = bp[1];
                #pragma unroll
                for (int j = 0; j < 4; j++) {
                    af[j] = (short)f2bf(b0[j]); af[4 + j] = (short)f2bf(b1v[j]);
                }
            }
            f32x4 c[8];
            #pragma unroll
            for (int t = 0; t < 8; t++) {
                short8 bw = *(const short8*)(BW2b + (size_t)(t * 64 + l) * 8);
                f32x4 z = {};
                c[t] = __builtin_amdgcn_mfma_f32_16x16x32_bf16(af, bw, z, 0, 0, 0);
            }
            float s[4];
            #pragma unroll
            for (int r = 0; r < 4; r++) {
                int e = e0 + lg * 4 + r;
                int src = esrc[e];
                short8 u = *(const short8*)(U + (size_t)src * 128 + lr * 8);
                float a0 = 0.f;
                #pragma unroll
                for (int t = 0; t < 8; t++)
                    a0 = fmaf(aw[t], lrelu_(c[t][r] + bf2f((unsigned short)u[t])), a0);
                s[r] = a0;
            }
            #pragma unroll
            for (int mk = 1; mk <= 8; mk <<= 1)
                #pragma unroll
                for (int r = 0; r < 4; r++) s[r] += __shfl_xor(s[r], mk, 16);
            if (lr == 0) {
                float anode = adst[n];
                #pragma unroll
                for (int r = 0; r < 4; r++)
                    lgS[w * 4 + nn][lg * 4 + r] = lrelu_(anode + ab + s[r]);
            }
        }
        __syncthreads();   // lgS ready
    }

    // ---- aggregation: node srow, edge-lane q ----
    {
        const int q = tid & 15;
        const int gnode = m0 + srow;
        const int e = gnode * 16 + q;
        const int src = esrc[e];
        float lgt;
        if (AGGMODE == 0) lgt = lgS[srow][q];
        else              lgt = lrelu_(aD[gnode] + bS[src] + b1[0]);
        float mx = lgt;
        #pragma unroll
        for (int mk = 1; mk <= 8; mk <<= 1) mx = fmaxf(mx, __shfl_xor(mx, mk, 16));
        float ex = __expf(lgt - mx);
        float den = ex;
        #pragma unroll
        for (int mk = 1; mk <= 8; mk <<= 1) den += __shfl_xor(den, mk, 16);
        float wq = ex / den;
        float s[8] = {};
        #pragma unroll
        for (int i = 0; i < 16; i++) {
            float wi = __shfl(wq, i, 16);
            int si = __shfl(src, i, 16);
            const unsigned short* vp = V + (size_t)si * 128 + q * 4;
            u16x4 v0 = *(const u16x4*)vp;
            #pragma unroll
            for (int j = 0; j < 4; j++) s[j] = fmaf(wi, bf2f(v0[j]), s[j]);
            u16x4 v1 = *(const u16x4*)(vp + 64);
            #pragma unroll
            for (int j = 0; j < 4; j++) s[4 + j] = fmaf(wi, bf2f(v1[j]), s[4 + j]);
        }
        u16x4 o0, o1;
        #pragma unroll
        for (int j = 0; j < 4; j++) { o0[j] = f2bf(s[j]); o1[j] = f2bf(s[4 + j]); }
        *(u16x4*)&aggS[srow][q * 4] = o0;
        *(u16x4*)&aggS[srow][64 + q * 4] = o1;
    }
    __syncthreads();   // aggS (and hpS) ready

    // ---- phase 1: pre-GEMM (aggS) + hh GEMMs (hpS) ----
    f32x4 accp[2] = {};
    f32x4 ah[2][3] = {};
    #pragma unroll
    for (int ko = 0; ko < 4; ko++) {
        short8 afA[2], afh[2];
        #pragma unroll
        for (int rt = 0; rt < 2; rt++) {
            afA[rt] = *(const short8*)&aggS[rt * 16 + lr][ko * 32 + lg * 8];
            afh[rt] = *(const short8*)&hpS[rt * 16 + lr][ko * 32 + lg * 8];
        }
        short8 bfp = *(const short8*)(Bpre + ((size_t)(w * 4 + ko) * 64 + l) * 8);
        #pragma unroll
        for (int rt = 0; rt < 2; rt++)
            accp[rt] = __builtin_amdgcn_mfma_f32_16x16x32_bf16(afA[rt], bfp, accp[rt], 0, 0, 0);
        #pragma unroll
        for (int g = 0; g < 3; g++) {
            short8 bh = *(const short8*)(Bhh + ((size_t)((w + 8 * g) * 4 + ko) * 64 + l) * 8);
            #pragma unroll
            for (int rt = 0; rt < 2; rt++)
                ah[rt][g] = __builtin_amdgcn_mfma_f32_16x16x32_bf16(afh[rt], bh, ah[rt][g], 0, 0, 0);
        }
    }
    {
        const int col = w * 16 + lr;
        const float bb = bpre[col];
        #pragma unroll
        for (int rt = 0; rt < 2; rt++)
            #pragma unroll
            for (int r = 0; r < 4; r++)
                ctxS[rt * 16 + lg * 4 + r][col] = f2bf(elu_(accp[rt][r] + bb));
    }
    __syncthreads();   // ctxS ready

    // ---- phase 2: ih GEMMs + gates ----
    f32x4 ai[2][3] = {};
    #pragma unroll
    for (int ko = 0; ko < 4; ko++) {
        short8 afc[2];
        #pragma unroll
        for (int rt = 0; rt < 2; rt++)
            afc[rt] = *(const short8*)&ctxS[rt * 16 + lr][ko * 32 + lg * 8];
        #pragma unroll
        for (int g = 0; g < 3; g++) {
            short8 bi = *(const short8*)(Bih + ((size_t)((w + 8 * g) * 4 + ko) * 64 + l) * 8);
            #pragma unroll
            for (int rt = 0; rt < 2; rt++)
                ai[rt][g] = __builtin_amdgcn_mfma_f32_16x16x32_bf16(afc[rt], bi, ai[rt][g], 0, 0, 0);
        }
    }
    {
        const int c = w * 16 + lr;
        const float br = bih[c] + bhh[c];
        const float bz = bih[c + 128] + bhh[c + 128];
        const float bin_ = bih[c + 256];
        const float bhn = bhh[c + 256];
        #pragma unroll
        for (int rt = 0; rt < 2; rt++)
            #pragma unroll
            for (int r = 0; r < 4; r++) {
                const int lrow = rt * 16 + lg * 4 + r;
                float rg = sigmoidf_(ai[rt][0][r] + ah[rt][0][r] + br);
                float zg = sigmoidf_(ai[rt][1][r] + ah[rt][1][r] + bz);
                float ng = tanhf_(ai[rt][2][r] + bin_ + rg * (ah[rt][2][r] + bhn));
                float hp = bf2f(hpS[lrow][c]);
                hoS[lrow][c] = fmaf(zg, hp - ng, ng);
            }
    }
    __syncthreads();   // hoS ready

    // ---- coalesced h writes ----
    {
        float v[8];
        #pragma unroll
        for (int k = 0; k < 8; k++) v[k] = hoS[srow][sc0 + k];
        f32x4* dst = (f32x4*)(houtF + (size_t)(m0 + srow) * 128 + sc0);
        dst[0] = *(f32x4*)v;
        dst[1] = *(f32x4*)(v + 4);
        if (FINAL == 0) {
            short8 p;
            #pragma unroll
            for (int k = 0; k < 8; k++) p[k] = (short)f2bf(v[k]);
            *(short8*)(houtBf + (size_t)(m0 + srow) * 128 + sc0) = p;
        }
    }

    if (FRONT) {
        int row = tid >> 4, q = tid & 15;
        float pa = 0.f, pb = 0.f;
        #pragma unroll
        for (int j = 0; j < 8; j++) {
            float x = hoS[row][q * 8 + j];
            pa = fmaf(x, w2att[q * 8 + j], pa);
            pb = fmaf(x, w2att[128 + q * 8 + j], pb);
        }
        #pragma unroll
        for (int m = 1; m <= 8; m <<= 1) {
            pa += __shfl_xor(pa, m, 16);
            pb += __shfl_xor(pb, m, 16);
        }
        if (q == 0) { aDOut[m0 + row] = pa; bSOut[m0 + row] = pb; }
    }

    if (FINAL) {
        // avg (coalesced) -> avgOut + ctxS(bf16)
        {
            const f32x4* p0 = (const f32x4*)(as0 + (size_t)(m0 + srow) * 128 + sc0);
            const f32x4* p1 = (const f32x4*)(as1 + (size_t)(m0 + srow) * 128 + sc0);
            f32x4* pav = (f32x4*)(avgOut + (size_t)(m0 + srow) * 128 + sc0);
            #pragma unroll
            for (int k = 0; k < 2; k++) {
                f32x4 x0 = p0[k], x1 = p1[k];
                f32x4 av;
                #pragma unroll
                for (int j = 0; j < 4; j++)
                    av[j] = (x0[j] + x1[j] + hoS[srow][sc0 + k * 4 + j]) * (1.f / 3.f);
                pav[k] = av;
                #pragma unroll
                for (int j = 0; j < 4; j++) ctxS[srow][sc0 + k * 4 + j] = f2bf(av[j]);
            }
        }
        __syncthreads();
        // lin GEMM: wave w -> col-tile w, 2 row-tiles
        f32x4 acc2[2] = {};
        #pragma unroll
        for (int ko = 0; ko < 4; ko++) {
            short8 bf = *(const short8*)(Blin + ((size_t)(w * 4 + ko) * 64 + l) * 8);
            #pragma unroll
            for (int rt = 0; rt < 2; rt++) {
                short8 af = *(const short8*)&ctxS[rt * 16 + lr][ko * 32 + lg * 8];
                acc2[rt] = __builtin_amdgcn_mfma_f32_16x16x32_bf16(af, bf, acc2[rt], 0, 0, 0);
            }
        }
        __syncthreads();
        {
            const int col = w * 16 + lr;
            const float bb = linb[col];
            #pragma unroll
            for (int rt = 0; rt < 2; rt++)
                #pragma unroll
                for (int r = 0; r < 4; r++) {
                    float vv = acc2[rt][r] + bb;
                    hoS[rt * 16 + lg * 4 + r][col] =
                        0.5f * vv * (1.f + erff(vv * 0.70710678118654752f));
                }
        }
        __syncthreads();
        {
            float v[8];
            #pragma unroll
            for (int k = 0; k < 8; k++) v[k] = hoS[srow][sc0 + k];
            f32x4* dst = (f32x4*)(outF + (size_t)(m0 + srow) * 128 + sc0);
            dst[0] = *(f32x4*)v;
            dst[1] = *(f32x4*)(v + 4);
        }
    }
}

extern "C" void kernel_launch(void* const* d_in, const int* in_sizes, int n_in,
                              void* d_out, int out_size, void* d_ws, size_t ws_size,
                              hipStream_t stream) {
    const float* atom     = (const float*)d_in[0];
    const int*   esrc     = (const int*)d_in[1];
    const float* bond     = (const float*)d_in[3];
    const float* fc1_w    = (const float*)d_in[4];
    const float* fc1_b    = (const float*)d_in[5];
    const float* fc2_w    = (const float*)d_in[6];
    const float* fc2_b    = (const float*)d_in[7];
    const float* att_w    = (const float*)d_in[8];
    const float* att_b    = (const float*)d_in[9];
    const float* attend_w = (const float*)d_in[10];
    const float* attend_b = (const float*)d_in[11];
    const float* gih1     = (const float*)d_in[12];
    const float* ghh1     = (const float*)d_in[13];
    const float* bih1     = (const float*)d_in[14];
    const float* bhh1     = (const float*)d_in[15];
    const float* fc1v2_w  = (const float*)d_in[16];
    const float* fc1v2_b  = (const float*)d_in[17];
    const float* fc2v2_w  = (const float*)d_in[18];
    const float* fc2v2_b  = (const float*)d_in[19];
    const float* gih2     = (const float*)d_in[20];
    const float* ghh2     = (const float*)d_in[21];
    const float* bih2     = (const float*)d_in[22];
    const float* bhh2     = (const float*)d_in[23];
    const float* lin_w    = (const float*)d_in[24];
    const float* lin_b    = (const float*)d_in[25];

    char* wsb = (char*)d_ws;
    size_t off = 0;
    auto allocB = [&](size_t bytes) {
        size_t o = off; off = (off + bytes + 255) & ~(size_t)255; return o;
    };
    unsigned short* Bfc1   = (unsigned short*)(wsb + allocB(128 * 128 * 2));
    unsigned short* Batt   = (unsigned short*)(wsb + allocB(128 * 128 * 2));
    unsigned short* BW2a   = (unsigned short*)(wsb + allocB(128 * 128 * 2));
    unsigned short* BW2b   = (unsigned short*)(wsb + allocB(512 * 8 * 2));
    unsigned short* Bgih1  = (unsigned short*)(wsb + allocB(384 * 128 * 2));
    unsigned short* Bghh1  = (unsigned short*)(wsb + allocB(384 * 128 * 2));
    unsigned short* Bfc2v2 = (unsigned short*)(wsb + allocB(128 * 128 * 2));
    unsigned short* Bgih2  = (unsigned short*)(wsb + allocB(384 * 128 * 2));
    unsigned short* Bghh2  = (unsigned short*)(wsb + allocB(384 * 128 * 2));
    unsigned short* Blin   = (unsigned short*)(wsb + allocB(128 * 128 * 2));
    unsigned short* naBf   = (unsigned short*)(wsb + allocB((size_t)NN * 128 * 2));
    unsigned short* Ubf    = (unsigned short*)(wsb + allocB((size_t)NN * 128 * 2));
    unsigned short* h1Bf   = (unsigned short*)(wsb + allocB((size_t)NN * 128 * 2));
    unsigned short* h2Bf   = (unsigned short*)(wsb + allocB((size_t)NN * 128 * 2));
    float* adst   = (float*)(wsb + allocB((size_t)NN * 4));
    float* aD     = (float*)(wsb + allocB((size_t)NN * 4));
    float* bS     = (float*)(wsb + allocB((size_t)NN * 4));
    (void)ws_size;

    float* out0 = (float*)d_out;
    float* as0  = out0 + (size_t)NN * 128;
    float* as1  = as0 + (size_t)NN * 128;
    float* as2  = as1 + (size_t)NN * 128;
    float* g0   = out0 + (size_t)4 * NN * 128;
    float* avg  = out0 + (size_t)5 * NN * 128;

    PackArgs pa;
    pa.d[0] = { fc1_w,    Bfc1,   128, 128, 0 };
    pa.d[1] = { attend_w, Batt,   128, 128, 0 };
    pa.d[2] = { fc2_w,    BW2a,   128, 144, 0 };
    pa.d[3] = { gih1,     Bgih1,  384, 128, 0 };
    pa.d[4] = { ghh1,     Bghh1,  384, 128, 0 };
    pa.d[5] = { fc2v2_w,  Bfc2v2, 128, 128, 0 };
    pa.d[6] = { gih2,     Bgih2,  384, 128, 0 };
    pa.d[7] = { ghh2,     Bghh2,  384, 128, 0 };
    pa.d[8] = { lin_w,    Blin,   128, 128, 0 };
    pa.d[9] = { fc2_w,    BW2b,   0,   0,   1 };
    k_pack<<<dim3(24, 10), 256, 0, stream>>>(pa);

    const int GB = NN / 16;     // 1250
    const int GB32 = NN / 32;   // 625

    // ---- V1 front ----
    k_v1_front<<<GB, 256, 0, stream>>>(atom, Bfc1, BW2a, fc1_b, fc2_b, att_w,
                                       g0, naBf, Ubf, adst);
    // ---- V1: fused logits + agg + GRU + front(layer2) ----
    k_gru<0, 1, 0><<<GB32, 512, 0, stream>>>(
        nullptr, nullptr, nullptr,
        bond, BW2b, att_w, att_b, adst, Ubf,
        esrc, naBf,
        Batt, attend_b,
        Bgih1, Bghh1, bih1, bhh1, naBf, as0, h1Bf,
        fc1v2_w, aD, bS,
        nullptr, nullptr, nullptr, nullptr, nullptr, nullptr);

    // ---- V2 layer 2 ----
    k_gru<1, 1, 0><<<GB32, 512, 0, stream>>>(
        aD, bS, fc1v2_b,
        nullptr, nullptr, nullptr, nullptr, nullptr, nullptr,
        esrc, h1Bf,
        Bfc2v2, fc2v2_b,
        Bgih2, Bghh2, bih2, bhh2, h1Bf, as1, h2Bf,
        fc1v2_w, aD, bS,
        nullptr, nullptr, nullptr, nullptr, nullptr, nullptr);

    // ---- V2 layer 3 + final ----
    k_gru<1, 0, 1><<<GB32, 512, 0, stream>>>(
        aD, bS, fc1v2_b,
        nullptr, nullptr, nullptr, nullptr, nullptr, nullptr,
        esrc, h2Bf,
        Bfc2v2, fc2v2_b,
        Bgih2, Bghh2, bih2, bhh2, h2Bf, as2, nullptr,
        nullptr, nullptr, nullptr,
        as0, as1, Blin, lin_b, avg, out0);
}